// Round 3
// baseline (1325.690 us; speedup 1.0000x reference)
//
#include <hip/hip_runtime.h>
#include <hip/hip_bf16.h>

#define N_NODES 50000
#define E_EDGES 800000
#define ETOT (E_EDGES + N_NODES)
#define HC 256
#define NHEAD 4
#define CHAN 64
#define NEG 0.2f

typedef _Float16 half8 __attribute__((ext_vector_type(8)));
typedef _Float16 half4v __attribute__((ext_vector_type(4)));
typedef float float4v __attribute__((ext_vector_type(4)));

// ---------------- CSR build (once per call; shared across all 5 layers) ----------------

__global__ void count_kernel(const int* __restrict__ ei, int* __restrict__ counts) {
    int i = blockIdx.x * blockDim.x + threadIdx.x;
    if (i >= ETOT) return;
    int dst = (i < E_EDGES) ? ei[E_EDGES + i] : (i - E_EDGES);
    atomicAdd(&counts[dst], 1);
}

// 1024 threads, thread-serial chunks (ceil(N/1024)=49) + one 10-step block scan.
__global__ __launch_bounds__(1024) void scan_kernel(const int* __restrict__ counts,
                                                    int* __restrict__ offsets,
                                                    int* __restrict__ cursor) {
    __shared__ int s[1024];
    int tid = threadIdx.x;
    const int CH = (N_NODES + 1023) / 1024;
    int lo = tid * CH;
    int hi = lo + CH; if (hi > N_NODES) hi = N_NODES;
    int sum = 0;
    for (int i = lo; i < hi; ++i) sum += counts[i];
    s[tid] = sum;
    __syncthreads();
    for (int off = 1; off < 1024; off <<= 1) {
        int t = (tid >= off) ? s[tid - off] : 0;
        __syncthreads();
        s[tid] += t;
        __syncthreads();
    }
    int run = s[tid] - sum;   // exclusive prefix of this chunk
    for (int i = lo; i < hi; ++i) {
        int c = counts[i];
        offsets[i] = run; cursor[i] = run;
        run += c;
    }
    if (tid == 1023) offsets[N_NODES] = run;
}

__global__ void fill_kernel(const int* __restrict__ ei, int* __restrict__ cursor,
                            int* __restrict__ csr_src) {
    int i = blockIdx.x * blockDim.x + threadIdx.x;
    if (i >= ETOT) return;
    int src, dst;
    if (i < E_EDGES) { src = ei[i]; dst = ei[E_EDGES + i]; }
    else             { src = i - E_EDGES; dst = src; }
    int pos = atomicAdd(&cursor[dst], 1);
    csr_src[pos] = src;
}

// ---------------- weight pre-split: W[K][256] fp32 -> Wt_h/Wt_l [n][k] f16 ----------------

__global__ void wsplit_kernel(const float* __restrict__ W, _Float16* __restrict__ Wth,
                              _Float16* __restrict__ Wtl, int K) {
    int id = blockIdx.x * 256 + threadIdx.x;
    if (id >= K * 256) return;
    int n = id & 255, k = id >> 8;
    float w = W[(size_t)k * 256 + n];
    _Float16 h = (_Float16)w;
    _Float16 l = (_Float16)(w - (float)h);
    Wth[(size_t)n * K + k] = h;
    Wtl[(size_t)n * K + k] = l;
}

// ---------------- f16-split MFMA GEMM: H[M,256] = (A1 (+A2)) @ W[K,256] ----------------

#define LDK 40

__global__ __launch_bounds__(256) void gemm_mfma_kernel(
        const float* __restrict__ A1, const float* __restrict__ A2,
        const _Float16* __restrict__ Wth, const _Float16* __restrict__ Wtl,
        float* __restrict__ H, int M, int K) {
    __shared__ _Float16 Ah[128][LDK];
    __shared__ _Float16 Al[128][LDK];
    __shared__ _Float16 Bh[128][LDK];
    __shared__ _Float16 Bl[128][LDK];

    int tid = threadIdx.x;
    int m0 = blockIdx.x * 128;
    int n0 = blockIdx.y * 128;
    int w = tid >> 6, lane = tid & 63;
    int rm = (w & 1) * 64, rn = (w >> 1) * 64;
    int fr = lane & 15;
    int fk = (lane >> 4) * 8;

    int ar = tid >> 3;
    int ak = (tid & 7) * 4;
    int wr = tid >> 2;
    int wk = (tid & 3) * 8;

    float4v acc[4][4];
    #pragma unroll
    for (int i = 0; i < 4; ++i)
        #pragma unroll
        for (int j = 0; j < 4; ++j)
            acc[i][j] = (float4v){0.f, 0.f, 0.f, 0.f};

    for (int k0 = 0; k0 < K; k0 += 32) {
        __syncthreads();
        #pragma unroll
        for (int g = 0; g < 4; ++g) {
            int r = g * 32 + ar;
            int row = m0 + r;
            float4 v = make_float4(0.f, 0.f, 0.f, 0.f);
            if (row < M) {
                v = *(const float4*)(A1 + (size_t)row * K + k0 + ak);
                if (A2) {
                    float4 u = *(const float4*)(A2 + (size_t)row * K + k0 + ak);
                    v.x += u.x; v.y += u.y; v.z += u.z; v.w += u.w;
                }
            }
            half4v hv = {(_Float16)v.x, (_Float16)v.y, (_Float16)v.z, (_Float16)v.w};
            half4v lv = {(_Float16)(v.x - (float)hv[0]), (_Float16)(v.y - (float)hv[1]),
                         (_Float16)(v.z - (float)hv[2]), (_Float16)(v.w - (float)hv[3])};
            *(half4v*)&Ah[r][ak] = hv;
            *(half4v*)&Al[r][ak] = lv;
        }
        #pragma unroll
        for (int g = 0; g < 2; ++g) {
            int r = g * 64 + wr;
            const _Float16* ph = Wth + (size_t)(n0 + r) * K + k0 + wk;
            const _Float16* pl = Wtl + (size_t)(n0 + r) * K + k0 + wk;
            *(half8*)&Bh[r][wk] = *(const half8*)ph;
            *(half8*)&Bl[r][wk] = *(const half8*)pl;
        }
        __syncthreads();
        half8 afh[4], afl[4], bfh[4], bfl[4];
        #pragma unroll
        for (int t = 0; t < 4; ++t) {
            afh[t] = *(const half8*)&Ah[rm + t * 16 + fr][fk];
            afl[t] = *(const half8*)&Al[rm + t * 16 + fr][fk];
            bfh[t] = *(const half8*)&Bh[rn + t * 16 + fr][fk];
            bfl[t] = *(const half8*)&Bl[rn + t * 16 + fr][fk];
        }
        #pragma unroll
        for (int tm = 0; tm < 4; ++tm)
            #pragma unroll
            for (int tn = 0; tn < 4; ++tn) {
                float4v c = acc[tm][tn];
                c = __builtin_amdgcn_mfma_f32_16x16x32_f16(afl[tm], bfh[tn], c, 0, 0, 0);
                c = __builtin_amdgcn_mfma_f32_16x16x32_f16(afh[tm], bfl[tn], c, 0, 0, 0);
                c = __builtin_amdgcn_mfma_f32_16x16x32_f16(afh[tm], bfh[tn], c, 0, 0, 0);
                acc[tm][tn] = c;
            }
    }
    #pragma unroll
    for (int tm = 0; tm < 4; ++tm) {
        int rbase = m0 + rm + tm * 16 + (lane >> 4) * 4;
        #pragma unroll
        for (int i = 0; i < 4; ++i) {
            int row = rbase + i;
            if (row < M) {
                #pragma unroll
                for (int tn = 0; tn < 4; ++tn)
                    H[(size_t)row * HC + n0 + rn + tn * 16 + fr] = acc[tm][tn][i];
            }
        }
    }
}

// ---------------- per-node attention logits ----------------

__global__ __launch_bounds__(256) void esed_kernel(const float* __restrict__ H,
                                                   const float* __restrict__ a_src,
                                                   const float* __restrict__ a_dst,
                                                   float* __restrict__ es, float* __restrict__ ed) {
    int tid = threadIdx.x;
    int lane = tid & 63;
    int node = blockIdx.x * 4 + (tid >> 6);
    int head = lane >> 4;
    int cc = (lane & 15) * 4;
    float4 h4 = *(const float4*)(H + (size_t)node * HC + lane * 4);
    float4 as = *(const float4*)(a_src + head * CHAN + cc);
    float4 ad = *(const float4*)(a_dst + head * CHAN + cc);
    float ps = h4.x * as.x + h4.y * as.y + h4.z * as.z + h4.w * as.w;
    float pd = h4.x * ad.x + h4.y * ad.y + h4.z * ad.z + h4.w * ad.w;
    #pragma unroll
    for (int m = 1; m < 16; m <<= 1) {
        ps += __shfl_xor(ps, m, 64);
        pd += __shfl_xor(pd, m, 64);
    }
    if ((lane & 15) == 0) {
        es[node * NHEAD + head] = ps;
        ed[node * NHEAD + head] = pd;
    }
}

// ---------------- fused edge-softmax + aggregation: ONE WAVE per dst node ----------------
// Fast path (deg<=64, ~always): lane j owns edge j. Softmax via plain max/sum
// butterflies; alpha4 cached in per-wave LDS; src ids broadcast via shfl.
// Gather loop has ZERO dependent global loads besides the H row itself.

__global__ __launch_bounds__(256) void gat_aggregate_kernel(
        const float* __restrict__ H, const float* __restrict__ es, const float* __restrict__ ed,
        const int* __restrict__ offsets, const int* __restrict__ csr_src,
        const float* __restrict__ bias, float* __restrict__ out, int do_relu) {
    __shared__ float alpha_lds[4][256];
    int tid = threadIdx.x;
    int w = tid >> 6, lane = tid & 63;
    int n = blockIdx.x * 4 + w;
    int off = offsets[n];
    int deg = offsets[n + 1] - off;
    int head = lane >> 4;
    float4 edv = *(const float4*)(ed + (size_t)n * 4);
    float4 acc = make_float4(0.f, 0.f, 0.f, 0.f);

    if (deg <= 64) {
        // --- lane = edge ---
        int sreg = 0;
        float4 e4 = make_float4(-1e30f, -1e30f, -1e30f, -1e30f);
        if (lane < deg) {
            sreg = csr_src[off + lane];
            float4 esv = *(const float4*)(es + (size_t)sreg * 4);
            e4.x = esv.x + edv.x; e4.y = esv.y + edv.y;
            e4.z = esv.z + edv.z; e4.w = esv.w + edv.w;
            e4.x = (e4.x > 0.f) ? e4.x : NEG * e4.x;
            e4.y = (e4.y > 0.f) ? e4.y : NEG * e4.y;
            e4.z = (e4.z > 0.f) ? e4.z : NEG * e4.z;
            e4.w = (e4.w > 0.f) ? e4.w : NEG * e4.w;
        }
        float4 m4 = e4;
        #pragma unroll
        for (int msk = 1; msk < 64; msk <<= 1) {
            m4.x = fmaxf(m4.x, __shfl_xor(m4.x, msk, 64));
            m4.y = fmaxf(m4.y, __shfl_xor(m4.y, msk, 64));
            m4.z = fmaxf(m4.z, __shfl_xor(m4.z, msk, 64));
            m4.w = fmaxf(m4.w, __shfl_xor(m4.w, msk, 64));
        }
        float4 ex4 = make_float4(0.f, 0.f, 0.f, 0.f);
        if (lane < deg) {
            ex4.x = __expf(e4.x - m4.x); ex4.y = __expf(e4.y - m4.y);
            ex4.z = __expf(e4.z - m4.z); ex4.w = __expf(e4.w - m4.w);
        }
        float4 l4 = ex4;
        #pragma unroll
        for (int msk = 1; msk < 64; msk <<= 1) {
            l4.x += __shfl_xor(l4.x, msk, 64);
            l4.y += __shfl_xor(l4.y, msk, 64);
            l4.z += __shfl_xor(l4.z, msk, 64);
            l4.w += __shfl_xor(l4.w, msk, 64);
        }
        float4 a4;
        a4.x = ex4.x / (l4.x + 1e-16f);
        a4.y = ex4.y / (l4.y + 1e-16f);
        a4.z = ex4.z / (l4.z + 1e-16f);
        a4.w = ex4.w / (l4.w + 1e-16f);
        *(float4*)&alpha_lds[w][lane * 4] = a4;   // same-wave write+read: no barrier

        // --- gather: lane = 4 channels; per edge one LDS read + one dwordx4 load ---
        #pragma unroll 4
        for (int j = 0; j < deg; ++j) {
            int s = __shfl(sreg, j, 64);
            float alpha = alpha_lds[w][j * 4 + head];
            float4 h4 = *(const float4*)(H + (size_t)s * HC + lane * 4);
            acc.x += alpha * h4.x; acc.y += alpha * h4.y;
            acc.z += alpha * h4.z; acc.w += alpha * h4.w;
        }
    } else {
        // --- generic fallback (deg > 64): online softmax + serial recompute ---
        float m[4] = {-1e30f, -1e30f, -1e30f, -1e30f};
        float l[4] = {0.f, 0.f, 0.f, 0.f};
        for (int base = 0; base < deg; base += 64) {
            int j = base + lane;
            if (j < deg) {
                int s = csr_src[off + j];
                float4 esv = *(const float4*)(es + (size_t)s * 4);
                float e[4] = {esv.x + edv.x, esv.y + edv.y, esv.z + edv.z, esv.w + edv.w};
                #pragma unroll
                for (int h = 0; h < 4; ++h) {
                    e[h] = (e[h] > 0.f) ? e[h] : NEG * e[h];
                    float M2 = fmaxf(m[h], e[h]);
                    l[h] = l[h] * __expf(m[h] - M2) + __expf(e[h] - M2);
                    m[h] = M2;
                }
            }
        }
        #pragma unroll
        for (int msk = 1; msk < 64; msk <<= 1) {
            #pragma unroll
            for (int h = 0; h < 4; ++h) {
                float mo = __shfl_xor(m[h], msk, 64);
                float lo = __shfl_xor(l[h], msk, 64);
                float M2 = fmaxf(m[h], mo);
                l[h] = l[h] * __expf(m[h] - M2) + lo * __expf(mo - M2);
                m[h] = M2;
            }
        }
        float fm = m[head];
        float fr = 1.f / (l[head] + 1e-16f);
        float edh = ((const float*)&edv)[head];
        for (int j = 0; j < deg; ++j) {
            int s = csr_src[off + j];
            float e = es[(size_t)s * 4 + head] + edh;
            e = (e > 0.f) ? e : NEG * e;
            float alpha = __expf(e - fm) * fr;
            float4 h4 = *(const float4*)(H + (size_t)s * HC + lane * 4);
            acc.x += alpha * h4.x; acc.y += alpha * h4.y;
            acc.z += alpha * h4.z; acc.w += alpha * h4.w;
        }
    }

    float4 b4 = *(const float4*)(bias + lane * 4);
    float4 o;
    o.x = acc.x + b4.x; o.y = acc.y + b4.y;
    o.z = acc.z + b4.z; o.w = acc.w + b4.w;
    if (do_relu) {
        o.x = fmaxf(o.x, 0.f); o.y = fmaxf(o.y, 0.f);
        o.z = fmaxf(o.z, 0.f); o.w = fmaxf(o.w, 0.f);
    }
    *(float4*)(out + (size_t)n * HC + lane * 4) = o;
}

// ---------------- launch ----------------

extern "C" void kernel_launch(void* const* d_in, const int* in_sizes, int n_in,
                              void* d_out, int out_size, void* d_ws, size_t ws_size,
                              hipStream_t stream) {
    const float* x  = (const float*)d_in[0];
    const int*   ei = (const int*)d_in[1];
    const float *W[5], *Asrc[5], *Adst[5], *Bs[5];
    for (int l = 0; l < 4; ++l) {
        W[l]    = (const float*)d_in[2 + l * 4];
        Asrc[l] = (const float*)d_in[3 + l * 4];
        Adst[l] = (const float*)d_in[4 + l * 4];
        Bs[l]   = (const float*)d_in[5 + l * 4];
    }
    W[4] = W[3]; Asrc[4] = Asrc[3]; Adst[4] = Adst[3]; Bs[4] = Bs[3];

    char* ws = (char*)d_ws;
    size_t off = 0;
    auto alloc = [&](size_t bytes) -> void* {
        void* p = ws + off;
        off += (bytes + 255) & ~(size_t)255;
        return p;
    };
    float* h       = (float*)alloc((size_t)N_NODES * HC * 4);
    float* xa      = (float*)alloc((size_t)N_NODES * HC * 4);
    float* xb      = (float*)alloc((size_t)N_NODES * HC * 4);
    float* xc      = (float*)alloc((size_t)N_NODES * HC * 4);
    float* es      = (float*)alloc((size_t)N_NODES * 4 * 4);
    float* ed      = (float*)alloc((size_t)N_NODES * 4 * 4);
    int*   counts  = (int*)alloc((size_t)N_NODES * 4);
    int*   offsets = (int*)alloc((size_t)(N_NODES + 1) * 4);
    int*   cursor  = (int*)alloc((size_t)N_NODES * 4);
    int*   csr_src = (int*)alloc((size_t)ETOT * 4);
    _Float16 *Wth[5], *Wtl[5];
    int Ks[4] = {128, 256, 256, 256};
    for (int l = 0; l < 4; ++l) {
        Wth[l] = (_Float16*)alloc((size_t)256 * Ks[l] * 2);
        Wtl[l] = (_Float16*)alloc((size_t)256 * Ks[l] * 2);
    }
    Wth[4] = Wth[3]; Wtl[4] = Wtl[3];

    hipMemsetAsync(counts, 0, (size_t)N_NODES * 4, stream);
    count_kernel<<<(ETOT + 255) / 256, 256, 0, stream>>>(ei, counts);
    scan_kernel<<<1, 1024, 0, stream>>>(counts, offsets, cursor);
    fill_kernel<<<(ETOT + 255) / 256, 256, 0, stream>>>(ei, cursor, csr_src);
    for (int l = 0; l < 4; ++l)
        wsplit_kernel<<<(Ks[l] * 256 + 255) / 256, 256, 0, stream>>>(W[l], Wth[l], Wtl[l], Ks[l]);

    auto layer = [&](const float* in1, const float* in2, int K, int l, float* outp, int relu) {
        dim3 g((N_NODES + 127) / 128, 2);
        gemm_mfma_kernel<<<g, 256, 0, stream>>>(in1, in2, Wth[l], Wtl[l], h, N_NODES, K);
        esed_kernel<<<N_NODES / 4, 256, 0, stream>>>(h, Asrc[l], Adst[l], es, ed);
        gat_aggregate_kernel<<<N_NODES / 4, 256, 0, stream>>>(h, es, ed, offsets, csr_src,
                                                              Bs[l], outp, relu);
    };

    float* out = (float*)d_out;
    layer(x,  nullptr, 128, 0, xa, 1);  // x1 = relu(gat(x))
    layer(xa, nullptr, 256, 1, xb, 1);  // x2 = relu(gat(x1))
    layer(xb, xa,      256, 2, xc, 1);  // x3 = relu(gat(x2+x1))
    layer(xb, xc,      256, 3, xa, 1);  // x4 = relu(gat(x2+x3))
    layer(xa, xc,      256, 4, out, 0); // x5 = gat(x4+x3), no relu
}

// Round 4
// 1040.841 us; speedup vs baseline: 1.2737x; 1.2737x over previous
//
#include <hip/hip_runtime.h>
#include <hip/hip_bf16.h>

#define N_NODES 50000
#define E_EDGES 800000
#define ETOT (E_EDGES + N_NODES)
#define HC 256
#define NHEAD 4
#define CHAN 64
#define NEG 0.2f

typedef _Float16 half8 __attribute__((ext_vector_type(8)));
typedef _Float16 half4v __attribute__((ext_vector_type(4)));
typedef float float4v __attribute__((ext_vector_type(4)));

// ---------------- CSR build (once per call; shared across all 5 layers) ----------------

__global__ void count_kernel(const int* __restrict__ ei, int* __restrict__ counts) {
    int i = blockIdx.x * blockDim.x + threadIdx.x;
    if (i >= ETOT) return;
    int dst = (i < E_EDGES) ? ei[E_EDGES + i] : (i - E_EDGES);
    atomicAdd(&counts[dst], 1);
}

__global__ __launch_bounds__(1024) void scan_kernel(const int* __restrict__ counts,
                                                    int* __restrict__ offsets,
                                                    int* __restrict__ cursor) {
    __shared__ int s[1024];
    int tid = threadIdx.x;
    const int CH = (N_NODES + 1023) / 1024;
    int lo = tid * CH;
    int hi = lo + CH; if (hi > N_NODES) hi = N_NODES;
    int sum = 0;
    for (int i = lo; i < hi; ++i) sum += counts[i];
    s[tid] = sum;
    __syncthreads();
    for (int off = 1; off < 1024; off <<= 1) {
        int t = (tid >= off) ? s[tid - off] : 0;
        __syncthreads();
        s[tid] += t;
        __syncthreads();
    }
    int run = s[tid] - sum;
    for (int i = lo; i < hi; ++i) {
        int c = counts[i];
        offsets[i] = run; cursor[i] = run;
        run += c;
    }
    if (tid == 1023) offsets[N_NODES] = run;
}

__global__ void fill_kernel(const int* __restrict__ ei, int* __restrict__ cursor,
                            int* __restrict__ csr_src) {
    int i = blockIdx.x * blockDim.x + threadIdx.x;
    if (i >= ETOT) return;
    int src, dst;
    if (i < E_EDGES) { src = ei[i]; dst = ei[E_EDGES + i]; }
    else             { src = i - E_EDGES; dst = src; }
    int pos = atomicAdd(&cursor[dst], 1);
    csr_src[pos] = src;
}

// ---------------- weight pre-split: W[K][256] fp32 -> Wt_h/Wt_l [n][k] f16 ----------------

__global__ void wsplit_kernel(const float* __restrict__ W, _Float16* __restrict__ Wth,
                              _Float16* __restrict__ Wtl, int K) {
    int id = blockIdx.x * 256 + threadIdx.x;
    if (id >= K * 256) return;
    int n = id & 255, k = id >> 8;
    float w = W[(size_t)k * 256 + n];
    _Float16 h = (_Float16)w;
    _Float16 l = (_Float16)(w - (float)h);
    Wth[(size_t)n * K + k] = h;
    Wtl[(size_t)n * K + k] = l;
}

// ---------------- f16-split MFMA GEMM: H16[M,256] = f16((A1 (+A2)) @ W[K,256]) ----------------

#define LDK 40

__global__ __launch_bounds__(256) void gemm_mfma_kernel(
        const float* __restrict__ A1, const float* __restrict__ A2,
        const _Float16* __restrict__ Wth, const _Float16* __restrict__ Wtl,
        _Float16* __restrict__ H16, int M, int K) {
    __shared__ _Float16 Ah[128][LDK];
    __shared__ _Float16 Al[128][LDK];
    __shared__ _Float16 Bh[128][LDK];
    __shared__ _Float16 Bl[128][LDK];

    int tid = threadIdx.x;
    int m0 = blockIdx.x * 128;
    int n0 = blockIdx.y * 128;
    int w = tid >> 6, lane = tid & 63;
    int rm = (w & 1) * 64, rn = (w >> 1) * 64;
    int fr = lane & 15;
    int fk = (lane >> 4) * 8;

    int ar = tid >> 3;
    int ak = (tid & 7) * 4;
    int wr = tid >> 2;
    int wk = (tid & 3) * 8;

    float4v acc[4][4];
    #pragma unroll
    for (int i = 0; i < 4; ++i)
        #pragma unroll
        for (int j = 0; j < 4; ++j)
            acc[i][j] = (float4v){0.f, 0.f, 0.f, 0.f};

    for (int k0 = 0; k0 < K; k0 += 32) {
        __syncthreads();
        #pragma unroll
        for (int g = 0; g < 4; ++g) {
            int r = g * 32 + ar;
            int row = m0 + r;
            float4 v = make_float4(0.f, 0.f, 0.f, 0.f);
            if (row < M) {
                v = *(const float4*)(A1 + (size_t)row * K + k0 + ak);
                if (A2) {
                    float4 u = *(const float4*)(A2 + (size_t)row * K + k0 + ak);
                    v.x += u.x; v.y += u.y; v.z += u.z; v.w += u.w;
                }
            }
            half4v hv = {(_Float16)v.x, (_Float16)v.y, (_Float16)v.z, (_Float16)v.w};
            half4v lv = {(_Float16)(v.x - (float)hv[0]), (_Float16)(v.y - (float)hv[1]),
                         (_Float16)(v.z - (float)hv[2]), (_Float16)(v.w - (float)hv[3])};
            *(half4v*)&Ah[r][ak] = hv;
            *(half4v*)&Al[r][ak] = lv;
        }
        #pragma unroll
        for (int g = 0; g < 2; ++g) {
            int r = g * 64 + wr;
            const _Float16* ph = Wth + (size_t)(n0 + r) * K + k0 + wk;
            const _Float16* pl = Wtl + (size_t)(n0 + r) * K + k0 + wk;
            *(half8*)&Bh[r][wk] = *(const half8*)ph;
            *(half8*)&Bl[r][wk] = *(const half8*)pl;
        }
        __syncthreads();
        half8 afh[4], afl[4], bfh[4], bfl[4];
        #pragma unroll
        for (int t = 0; t < 4; ++t) {
            afh[t] = *(const half8*)&Ah[rm + t * 16 + fr][fk];
            afl[t] = *(const half8*)&Al[rm + t * 16 + fr][fk];
            bfh[t] = *(const half8*)&Bh[rn + t * 16 + fr][fk];
            bfl[t] = *(const half8*)&Bl[rn + t * 16 + fr][fk];
        }
        #pragma unroll
        for (int tm = 0; tm < 4; ++tm)
            #pragma unroll
            for (int tn = 0; tn < 4; ++tn) {
                float4v c = acc[tm][tn];
                c = __builtin_amdgcn_mfma_f32_16x16x32_f16(afl[tm], bfh[tn], c, 0, 0, 0);
                c = __builtin_amdgcn_mfma_f32_16x16x32_f16(afh[tm], bfl[tn], c, 0, 0, 0);
                c = __builtin_amdgcn_mfma_f32_16x16x32_f16(afh[tm], bfh[tn], c, 0, 0, 0);
                acc[tm][tn] = c;
            }
    }
    #pragma unroll
    for (int tm = 0; tm < 4; ++tm) {
        int rbase = m0 + rm + tm * 16 + (lane >> 4) * 4;
        #pragma unroll
        for (int i = 0; i < 4; ++i) {
            int row = rbase + i;
            if (row < M) {
                #pragma unroll
                for (int tn = 0; tn < 4; ++tn)
                    H16[(size_t)row * HC + n0 + rn + tn * 16 + fr] = (_Float16)acc[tm][tn][i];
            }
        }
    }
}

// ---------------- per-node attention logits (f16 H) ----------------

__global__ __launch_bounds__(256) void esed_kernel(const _Float16* __restrict__ H16,
                                                   const float* __restrict__ a_src,
                                                   const float* __restrict__ a_dst,
                                                   float* __restrict__ es, float* __restrict__ ed) {
    int tid = threadIdx.x;
    int lane = tid & 63;
    int node = blockIdx.x * 4 + (tid >> 6);
    int head = lane >> 4;
    int cc = (lane & 15) * 4;
    half4v hv = *(const half4v*)(H16 + (size_t)node * HC + lane * 4);
    float4 h4 = make_float4((float)hv[0], (float)hv[1], (float)hv[2], (float)hv[3]);
    float4 as = *(const float4*)(a_src + head * CHAN + cc);
    float4 ad = *(const float4*)(a_dst + head * CHAN + cc);
    float ps = h4.x * as.x + h4.y * as.y + h4.z * as.z + h4.w * as.w;
    float pd = h4.x * ad.x + h4.y * ad.y + h4.z * ad.z + h4.w * ad.w;
    #pragma unroll
    for (int m = 1; m < 16; m <<= 1) {
        ps += __shfl_xor(ps, m, 64);
        pd += __shfl_xor(pd, m, 64);
    }
    if ((lane & 15) == 0) {
        es[node * NHEAD + head] = ps;
        ed[node * NHEAD + head] = pd;
    }
}

// ---------------- fused edge-softmax + aggregation: ONE WAVE per dst node, f16 gather ----------------

__global__ __launch_bounds__(256) void gat_aggregate_kernel(
        const _Float16* __restrict__ H16, const float* __restrict__ es, const float* __restrict__ ed,
        const int* __restrict__ offsets, const int* __restrict__ csr_src,
        const float* __restrict__ bias, float* __restrict__ out, int do_relu) {
    __shared__ float alpha_lds[4][256];
    int tid = threadIdx.x;
    int w = tid >> 6, lane = tid & 63;
    int n = blockIdx.x * 4 + w;
    int off = offsets[n];
    int deg = offsets[n + 1] - off;
    int head = lane >> 4;
    float4 edv = *(const float4*)(ed + (size_t)n * 4);
    float4 acc0 = make_float4(0.f, 0.f, 0.f, 0.f);
    float4 acc1 = make_float4(0.f, 0.f, 0.f, 0.f);

    if (deg <= 64) {
        // --- lane = edge: compute alpha ---
        int sreg = 0;
        float4 e4 = make_float4(-1e30f, -1e30f, -1e30f, -1e30f);
        if (lane < deg) {
            sreg = csr_src[off + lane];
            float4 esv = *(const float4*)(es + (size_t)sreg * 4);
            e4.x = esv.x + edv.x; e4.y = esv.y + edv.y;
            e4.z = esv.z + edv.z; e4.w = esv.w + edv.w;
            e4.x = (e4.x > 0.f) ? e4.x : NEG * e4.x;
            e4.y = (e4.y > 0.f) ? e4.y : NEG * e4.y;
            e4.z = (e4.z > 0.f) ? e4.z : NEG * e4.z;
            e4.w = (e4.w > 0.f) ? e4.w : NEG * e4.w;
        }
        float4 m4 = e4;
        #pragma unroll
        for (int msk = 1; msk < 64; msk <<= 1) {
            m4.x = fmaxf(m4.x, __shfl_xor(m4.x, msk, 64));
            m4.y = fmaxf(m4.y, __shfl_xor(m4.y, msk, 64));
            m4.z = fmaxf(m4.z, __shfl_xor(m4.z, msk, 64));
            m4.w = fmaxf(m4.w, __shfl_xor(m4.w, msk, 64));
        }
        float4 ex4 = make_float4(0.f, 0.f, 0.f, 0.f);
        if (lane < deg) {
            ex4.x = __expf(e4.x - m4.x); ex4.y = __expf(e4.y - m4.y);
            ex4.z = __expf(e4.z - m4.z); ex4.w = __expf(e4.w - m4.w);
        }
        float4 l4 = ex4;
        #pragma unroll
        for (int msk = 1; msk < 64; msk <<= 1) {
            l4.x += __shfl_xor(l4.x, msk, 64);
            l4.y += __shfl_xor(l4.y, msk, 64);
            l4.z += __shfl_xor(l4.z, msk, 64);
            l4.w += __shfl_xor(l4.w, msk, 64);
        }
        float4 a4;
        a4.x = ex4.x / (l4.x + 1e-16f);
        a4.y = ex4.y / (l4.y + 1e-16f);
        a4.z = ex4.z / (l4.z + 1e-16f);
        a4.w = ex4.w / (l4.w + 1e-16f);
        *(float4*)&alpha_lds[w][lane * 4] = a4;   // same-wave write+read: no barrier

        // --- gather: paired edges, two accumulators, 4+ loads in flight ---
        int j = 0;
        #pragma unroll 2
        for (; j + 2 <= deg; j += 2) {
            int s0 = __shfl(sreg, j, 64);
            int s1 = __shfl(sreg, j + 1, 64);
            float al0 = alpha_lds[w][j * 4 + head];
            float al1 = alpha_lds[w][(j + 1) * 4 + head];
            half4v h0 = *(const half4v*)(H16 + (size_t)s0 * HC + lane * 4);
            half4v h1 = *(const half4v*)(H16 + (size_t)s1 * HC + lane * 4);
            acc0.x += al0 * (float)h0[0]; acc0.y += al0 * (float)h0[1];
            acc0.z += al0 * (float)h0[2]; acc0.w += al0 * (float)h0[3];
            acc1.x += al1 * (float)h1[0]; acc1.y += al1 * (float)h1[1];
            acc1.z += al1 * (float)h1[2]; acc1.w += al1 * (float)h1[3];
        }
        if (j < deg) {
            int s0 = __shfl(sreg, j, 64);
            float al0 = alpha_lds[w][j * 4 + head];
            half4v h0 = *(const half4v*)(H16 + (size_t)s0 * HC + lane * 4);
            acc0.x += al0 * (float)h0[0]; acc0.y += al0 * (float)h0[1];
            acc0.z += al0 * (float)h0[2]; acc0.w += al0 * (float)h0[3];
        }
    } else {
        // --- generic fallback (deg > 64) ---
        float m[4] = {-1e30f, -1e30f, -1e30f, -1e30f};
        float l[4] = {0.f, 0.f, 0.f, 0.f};
        for (int base = 0; base < deg; base += 64) {
            int j = base + lane;
            if (j < deg) {
                int s = csr_src[off + j];
                float4 esv = *(const float4*)(es + (size_t)s * 4);
                float e[4] = {esv.x + edv.x, esv.y + edv.y, esv.z + edv.z, esv.w + edv.w};
                #pragma unroll
                for (int h = 0; h < 4; ++h) {
                    e[h] = (e[h] > 0.f) ? e[h] : NEG * e[h];
                    float M2 = fmaxf(m[h], e[h]);
                    l[h] = l[h] * __expf(m[h] - M2) + __expf(e[h] - M2);
                    m[h] = M2;
                }
            }
        }
        #pragma unroll
        for (int msk = 1; msk < 64; msk <<= 1) {
            #pragma unroll
            for (int h = 0; h < 4; ++h) {
                float mo = __shfl_xor(m[h], msk, 64);
                float lo = __shfl_xor(l[h], msk, 64);
                float M2 = fmaxf(m[h], mo);
                l[h] = l[h] * __expf(m[h] - M2) + lo * __expf(mo - M2);
                m[h] = M2;
            }
        }
        float fm = m[head];
        float fr = 1.f / (l[head] + 1e-16f);
        float edh = ((const float*)&edv)[head];
        for (int j = 0; j < deg; ++j) {
            int s = csr_src[off + j];
            float e = es[(size_t)s * 4 + head] + edh;
            e = (e > 0.f) ? e : NEG * e;
            float alpha = __expf(e - fm) * fr;
            half4v h0 = *(const half4v*)(H16 + (size_t)s * HC + lane * 4);
            acc0.x += alpha * (float)h0[0]; acc0.y += alpha * (float)h0[1];
            acc0.z += alpha * (float)h0[2]; acc0.w += alpha * (float)h0[3];
        }
    }

    float4 b4 = *(const float4*)(bias + lane * 4);
    float4 o;
    o.x = acc0.x + acc1.x + b4.x; o.y = acc0.y + acc1.y + b4.y;
    o.z = acc0.z + acc1.z + b4.z; o.w = acc0.w + acc1.w + b4.w;
    if (do_relu) {
        o.x = fmaxf(o.x, 0.f); o.y = fmaxf(o.y, 0.f);
        o.z = fmaxf(o.z, 0.f); o.w = fmaxf(o.w, 0.f);
    }
    *(float4*)(out + (size_t)n * HC + lane * 4) = o;
}

// ---------------- launch ----------------

extern "C" void kernel_launch(void* const* d_in, const int* in_sizes, int n_in,
                              void* d_out, int out_size, void* d_ws, size_t ws_size,
                              hipStream_t stream) {
    const float* x  = (const float*)d_in[0];
    const int*   ei = (const int*)d_in[1];
    const float *W[5], *Asrc[5], *Adst[5], *Bs[5];
    for (int l = 0; l < 4; ++l) {
        W[l]    = (const float*)d_in[2 + l * 4];
        Asrc[l] = (const float*)d_in[3 + l * 4];
        Adst[l] = (const float*)d_in[4 + l * 4];
        Bs[l]   = (const float*)d_in[5 + l * 4];
    }
    W[4] = W[3]; Asrc[4] = Asrc[3]; Adst[4] = Adst[3]; Bs[4] = Bs[3];

    char* ws = (char*)d_ws;
    size_t off = 0;
    auto alloc = [&](size_t bytes) -> void* {
        void* p = ws + off;
        off += (bytes + 255) & ~(size_t)255;
        return p;
    };
    _Float16* h16  = (_Float16*)alloc((size_t)N_NODES * HC * 2);
    float* xa      = (float*)alloc((size_t)N_NODES * HC * 4);
    float* xb      = (float*)alloc((size_t)N_NODES * HC * 4);
    float* xc      = (float*)alloc((size_t)N_NODES * HC * 4);
    float* es      = (float*)alloc((size_t)N_NODES * 4 * 4);
    float* ed      = (float*)alloc((size_t)N_NODES * 4 * 4);
    int*   counts  = (int*)alloc((size_t)N_NODES * 4);
    int*   offsets = (int*)alloc((size_t)(N_NODES + 1) * 4);
    int*   cursor  = (int*)alloc((size_t)N_NODES * 4);
    int*   csr_src = (int*)alloc((size_t)ETOT * 4);
    _Float16 *Wth[5], *Wtl[5];
    int Ks[4] = {128, 256, 256, 256};
    for (int l = 0; l < 4; ++l) {
        Wth[l] = (_Float16*)alloc((size_t)256 * Ks[l] * 2);
        Wtl[l] = (_Float16*)alloc((size_t)256 * Ks[l] * 2);
    }
    Wth[4] = Wth[3]; Wtl[4] = Wtl[3];

    hipMemsetAsync(counts, 0, (size_t)N_NODES * 4, stream);
    count_kernel<<<(ETOT + 255) / 256, 256, 0, stream>>>(ei, counts);
    scan_kernel<<<1, 1024, 0, stream>>>(counts, offsets, cursor);
    fill_kernel<<<(ETOT + 255) / 256, 256, 0, stream>>>(ei, cursor, csr_src);
    for (int l = 0; l < 4; ++l)
        wsplit_kernel<<<(Ks[l] * 256 + 255) / 256, 256, 0, stream>>>(W[l], Wth[l], Wtl[l], Ks[l]);

    auto layer = [&](const float* in1, const float* in2, int K, int l, float* outp, int relu) {
        dim3 g((N_NODES + 127) / 128, 2);
        gemm_mfma_kernel<<<g, 256, 0, stream>>>(in1, in2, Wth[l], Wtl[l], h16, N_NODES, K);
        esed_kernel<<<N_NODES / 4, 256, 0, stream>>>(h16, Asrc[l], Adst[l], es, ed);
        gat_aggregate_kernel<<<N_NODES / 4, 256, 0, stream>>>(h16, es, ed, offsets, csr_src,
                                                              Bs[l], outp, relu);
    };

    float* out = (float*)d_out;
    layer(x,  nullptr, 128, 0, xa, 1);  // x1 = relu(gat(x))
    layer(xa, nullptr, 256, 1, xb, 1);  // x2 = relu(gat(x1))
    layer(xb, xa,      256, 2, xc, 1);  // x3 = relu(gat(x2+x1))
    layer(xb, xc,      256, 3, xa, 1);  // x4 = relu(gat(x2+x3))
    layer(xa, xc,      256, 4, out, 0); // x5 = gat(x4+x3), no relu
}

// Round 5
// 889.683 us; speedup vs baseline: 1.4901x; 1.1699x over previous
//
#include <hip/hip_runtime.h>
#include <hip/hip_bf16.h>

#define N_NODES 50000
#define E_EDGES 800000
#define ETOT (E_EDGES + N_NODES)
#define HC 256
#define NHEAD 4
#define CHAN 64
#define NEG 0.2f
#define NBLK ((N_NODES + 1023) / 1024)   // 49

typedef _Float16 half8 __attribute__((ext_vector_type(8)));
typedef _Float16 half4v __attribute__((ext_vector_type(4)));
typedef float float4v __attribute__((ext_vector_type(4)));

// ---------------- CSR build (once per call; shared across all 5 layers) ----------------

__global__ void count_kernel(const int* __restrict__ ei, int* __restrict__ counts) {
    int i = blockIdx.x * blockDim.x + threadIdx.x;
    if (i >= ETOT) return;
    int dst = (i < E_EDGES) ? ei[E_EDGES + i] : (i - E_EDGES);
    atomicAdd(&counts[dst], 1);
}

// 3-stage coalesced scan: blocksum -> single-wave scan -> scatter with block prefix
__global__ __launch_bounds__(256) void blocksum_kernel(const int* __restrict__ counts,
                                                       int* __restrict__ blocksums) {
    __shared__ int s[4];
    int b = blockIdx.x, tid = threadIdx.x;
    int base = b * 1024;
    int sum = 0;
    #pragma unroll
    for (int r = 0; r < 4; ++r) {
        int idx = base + r * 256 + tid;
        sum += (idx < N_NODES) ? counts[idx] : 0;
    }
    #pragma unroll
    for (int m = 1; m < 64; m <<= 1) sum += __shfl_xor(sum, m, 64);
    if ((tid & 63) == 0) s[tid >> 6] = sum;
    __syncthreads();
    if (tid == 0) blocksums[b] = s[0] + s[1] + s[2] + s[3];
}

__global__ __launch_bounds__(64) void blockscan_kernel(int* __restrict__ blocksums) {
    int tid = threadIdx.x;
    int v = (tid < NBLK) ? blocksums[tid] : 0;
    #pragma unroll
    for (int off = 1; off < 64; off <<= 1) {
        int t = __shfl_up(v, off, 64);
        if (tid >= off) v += t;
    }
    if (tid < NBLK) blocksums[tid] = v;   // inclusive
}

__global__ __launch_bounds__(1024) void scatter_scan_kernel(const int* __restrict__ counts,
                                                            const int* __restrict__ blocksums,
                                                            int* __restrict__ offsets,
                                                            int* __restrict__ cursor) {
    __shared__ int s[1024];
    int b = blockIdx.x, tid = threadIdx.x;
    int idx = b * 1024 + tid;
    int v = (idx < N_NODES) ? counts[idx] : 0;
    s[tid] = v;
    __syncthreads();
    for (int off = 1; off < 1024; off <<= 1) {
        int t = (tid >= off) ? s[tid - off] : 0;
        __syncthreads();
        s[tid] += t;
        __syncthreads();
    }
    int excl = s[tid] - v + (b > 0 ? blocksums[b - 1] : 0);
    if (idx < N_NODES) { offsets[idx] = excl; cursor[idx] = excl; }
    if (idx == N_NODES - 1) offsets[N_NODES] = excl + v;
}

__global__ void fill_kernel(const int* __restrict__ ei, int* __restrict__ cursor,
                            int* __restrict__ csr_src) {
    int i = blockIdx.x * blockDim.x + threadIdx.x;
    if (i >= ETOT) return;
    int src, dst;
    if (i < E_EDGES) { src = ei[i]; dst = ei[E_EDGES + i]; }
    else             { src = i - E_EDGES; dst = src; }
    int pos = atomicAdd(&cursor[dst], 1);
    csr_src[pos] = src;
}

// ---------------- weight pre-split: W[K][256] fp32 -> Wt_h/Wt_l [n][k] f16 ----------------

__global__ void wsplit_kernel(const float* __restrict__ W, _Float16* __restrict__ Wth,
                              _Float16* __restrict__ Wtl, int K) {
    int id = blockIdx.x * 256 + threadIdx.x;
    if (id >= K * 256) return;
    int n = id & 255, k = id >> 8;
    float w = W[(size_t)k * 256 + n];
    _Float16 h = (_Float16)w;
    _Float16 l = (_Float16)(w - (float)h);
    Wth[(size_t)n * K + k] = h;
    Wtl[(size_t)n * K + k] = l;
}

// ---------------- f16-split MFMA GEMM: H16[M,256] = f16((A1 (+A2)) @ W[K,256]) ----------------

#define LDK 40

__global__ __launch_bounds__(256) void gemm_mfma_kernel(
        const float* __restrict__ A1, const float* __restrict__ A2,
        const _Float16* __restrict__ Wth, const _Float16* __restrict__ Wtl,
        _Float16* __restrict__ H16, int M, int K) {
    __shared__ _Float16 Ah[128][LDK];
    __shared__ _Float16 Al[128][LDK];
    __shared__ _Float16 Bh[128][LDK];
    __shared__ _Float16 Bl[128][LDK];

    int tid = threadIdx.x;
    int m0 = blockIdx.x * 128;
    int n0 = blockIdx.y * 128;
    int w = tid >> 6, lane = tid & 63;
    int rm = (w & 1) * 64, rn = (w >> 1) * 64;
    int fr = lane & 15;
    int fk = (lane >> 4) * 8;

    int ar = tid >> 3;
    int ak = (tid & 7) * 4;
    int wr = tid >> 2;
    int wk = (tid & 3) * 8;

    float4v acc[4][4];
    #pragma unroll
    for (int i = 0; i < 4; ++i)
        #pragma unroll
        for (int j = 0; j < 4; ++j)
            acc[i][j] = (float4v){0.f, 0.f, 0.f, 0.f};

    for (int k0 = 0; k0 < K; k0 += 32) {
        __syncthreads();
        #pragma unroll
        for (int g = 0; g < 4; ++g) {
            int r = g * 32 + ar;
            int row = m0 + r;
            float4 v = make_float4(0.f, 0.f, 0.f, 0.f);
            if (row < M) {
                v = *(const float4*)(A1 + (size_t)row * K + k0 + ak);
                if (A2) {
                    float4 u = *(const float4*)(A2 + (size_t)row * K + k0 + ak);
                    v.x += u.x; v.y += u.y; v.z += u.z; v.w += u.w;
                }
            }
            half4v hv = {(_Float16)v.x, (_Float16)v.y, (_Float16)v.z, (_Float16)v.w};
            half4v lv = {(_Float16)(v.x - (float)hv[0]), (_Float16)(v.y - (float)hv[1]),
                         (_Float16)(v.z - (float)hv[2]), (_Float16)(v.w - (float)hv[3])};
            *(half4v*)&Ah[r][ak] = hv;
            *(half4v*)&Al[r][ak] = lv;
        }
        #pragma unroll
        for (int g = 0; g < 2; ++g) {
            int r = g * 64 + wr;
            const _Float16* ph = Wth + (size_t)(n0 + r) * K + k0 + wk;
            const _Float16* pl = Wtl + (size_t)(n0 + r) * K + k0 + wk;
            *(half8*)&Bh[r][wk] = *(const half8*)ph;
            *(half8*)&Bl[r][wk] = *(const half8*)pl;
        }
        __syncthreads();
        half8 afh[4], afl[4], bfh[4], bfl[4];
        #pragma unroll
        for (int t = 0; t < 4; ++t) {
            afh[t] = *(const half8*)&Ah[rm + t * 16 + fr][fk];
            afl[t] = *(const half8*)&Al[rm + t * 16 + fr][fk];
            bfh[t] = *(const half8*)&Bh[rn + t * 16 + fr][fk];
            bfl[t] = *(const half8*)&Bl[rn + t * 16 + fr][fk];
        }
        #pragma unroll
        for (int tm = 0; tm < 4; ++tm)
            #pragma unroll
            for (int tn = 0; tn < 4; ++tn) {
                float4v c = acc[tm][tn];
                c = __builtin_amdgcn_mfma_f32_16x16x32_f16(afl[tm], bfh[tn], c, 0, 0, 0);
                c = __builtin_amdgcn_mfma_f32_16x16x32_f16(afh[tm], bfl[tn], c, 0, 0, 0);
                c = __builtin_amdgcn_mfma_f32_16x16x32_f16(afh[tm], bfh[tn], c, 0, 0, 0);
                acc[tm][tn] = c;
            }
    }
    #pragma unroll
    for (int tm = 0; tm < 4; ++tm) {
        int rbase = m0 + rm + tm * 16 + (lane >> 4) * 4;
        #pragma unroll
        for (int i = 0; i < 4; ++i) {
            int row = rbase + i;
            if (row < M) {
                #pragma unroll
                for (int tn = 0; tn < 4; ++tn)
                    H16[(size_t)row * HC + n0 + rn + tn * 16 + fr] = (_Float16)acc[tm][tn][i];
            }
        }
    }
}

// ---------------- per-node attention logits (f16 H) ----------------

__global__ __launch_bounds__(256) void esed_kernel(const _Float16* __restrict__ H16,
                                                   const float* __restrict__ a_src,
                                                   const float* __restrict__ a_dst,
                                                   float* __restrict__ es, float* __restrict__ ed) {
    int tid = threadIdx.x;
    int lane = tid & 63;
    int node = blockIdx.x * 4 + (tid >> 6);
    int head = lane >> 4;
    int cc = (lane & 15) * 4;
    half4v hv = *(const half4v*)(H16 + (size_t)node * HC + lane * 4);
    float4 h4 = make_float4((float)hv[0], (float)hv[1], (float)hv[2], (float)hv[3]);
    float4 as = *(const float4*)(a_src + head * CHAN + cc);
    float4 ad = *(const float4*)(a_dst + head * CHAN + cc);
    float ps = h4.x * as.x + h4.y * as.y + h4.z * as.z + h4.w * as.w;
    float pd = h4.x * ad.x + h4.y * ad.y + h4.z * ad.z + h4.w * ad.w;
    #pragma unroll
    for (int m = 1; m < 16; m <<= 1) {
        ps += __shfl_xor(ps, m, 64);
        pd += __shfl_xor(pd, m, 64);
    }
    if ((lane & 15) == 0) {
        es[node * NHEAD + head] = ps;
        ed[node * NHEAD + head] = pd;
    }
}

// ---------------- fused edge-softmax + aggregation: ONE WAVE per dst node, f16 gather ----------------

__global__ __launch_bounds__(256) void gat_aggregate_kernel(
        const _Float16* __restrict__ H16, const float* __restrict__ es, const float* __restrict__ ed,
        const int* __restrict__ offsets, const int* __restrict__ csr_src,
        const float* __restrict__ bias, float* __restrict__ out, int do_relu) {
    __shared__ float alpha_lds[4][256];
    int tid = threadIdx.x;
    int w = tid >> 6, lane = tid & 63;
    int n = blockIdx.x * 4 + w;
    int off = offsets[n];
    int deg = offsets[n + 1] - off;
    int head = lane >> 4;
    float4 edv = *(const float4*)(ed + (size_t)n * 4);
    float4 acc0 = make_float4(0.f, 0.f, 0.f, 0.f);
    float4 acc1 = make_float4(0.f, 0.f, 0.f, 0.f);

    if (deg <= 64) {
        int sreg = 0;
        float4 e4 = make_float4(-1e30f, -1e30f, -1e30f, -1e30f);
        if (lane < deg) {
            sreg = csr_src[off + lane];
            float4 esv = *(const float4*)(es + (size_t)sreg * 4);
            e4.x = esv.x + edv.x; e4.y = esv.y + edv.y;
            e4.z = esv.z + edv.z; e4.w = esv.w + edv.w;
            e4.x = (e4.x > 0.f) ? e4.x : NEG * e4.x;
            e4.y = (e4.y > 0.f) ? e4.y : NEG * e4.y;
            e4.z = (e4.z > 0.f) ? e4.z : NEG * e4.z;
            e4.w = (e4.w > 0.f) ? e4.w : NEG * e4.w;
        }
        float4 m4 = e4;
        #pragma unroll
        for (int msk = 1; msk < 64; msk <<= 1) {
            m4.x = fmaxf(m4.x, __shfl_xor(m4.x, msk, 64));
            m4.y = fmaxf(m4.y, __shfl_xor(m4.y, msk, 64));
            m4.z = fmaxf(m4.z, __shfl_xor(m4.z, msk, 64));
            m4.w = fmaxf(m4.w, __shfl_xor(m4.w, msk, 64));
        }
        float4 ex4 = make_float4(0.f, 0.f, 0.f, 0.f);
        if (lane < deg) {
            ex4.x = __expf(e4.x - m4.x); ex4.y = __expf(e4.y - m4.y);
            ex4.z = __expf(e4.z - m4.z); ex4.w = __expf(e4.w - m4.w);
        }
        float4 l4 = ex4;
        #pragma unroll
        for (int msk = 1; msk < 64; msk <<= 1) {
            l4.x += __shfl_xor(l4.x, msk, 64);
            l4.y += __shfl_xor(l4.y, msk, 64);
            l4.z += __shfl_xor(l4.z, msk, 64);
            l4.w += __shfl_xor(l4.w, msk, 64);
        }
        float4 a4;
        a4.x = ex4.x / (l4.x + 1e-16f);
        a4.y = ex4.y / (l4.y + 1e-16f);
        a4.z = ex4.z / (l4.z + 1e-16f);
        a4.w = ex4.w / (l4.w + 1e-16f);
        *(float4*)&alpha_lds[w][lane * 4] = a4;   // same-wave write+read: no barrier

        // --- gather: 4 edges in flight, two accumulators ---
        int j = 0;
        #pragma unroll 2
        for (; j + 4 <= deg; j += 4) {
            int s0 = __shfl(sreg, j,     64);
            int s1 = __shfl(sreg, j + 1, 64);
            int s2 = __shfl(sreg, j + 2, 64);
            int s3 = __shfl(sreg, j + 3, 64);
            float al0 = alpha_lds[w][(j    ) * 4 + head];
            float al1 = alpha_lds[w][(j + 1) * 4 + head];
            float al2 = alpha_lds[w][(j + 2) * 4 + head];
            float al3 = alpha_lds[w][(j + 3) * 4 + head];
            half4v h0 = *(const half4v*)(H16 + (size_t)s0 * HC + lane * 4);
            half4v h1 = *(const half4v*)(H16 + (size_t)s1 * HC + lane * 4);
            half4v h2 = *(const half4v*)(H16 + (size_t)s2 * HC + lane * 4);
            half4v h3 = *(const half4v*)(H16 + (size_t)s3 * HC + lane * 4);
            acc0.x += al0 * (float)h0[0]; acc0.y += al0 * (float)h0[1];
            acc0.z += al0 * (float)h0[2]; acc0.w += al0 * (float)h0[3];
            acc1.x += al1 * (float)h1[0]; acc1.y += al1 * (float)h1[1];
            acc1.z += al1 * (float)h1[2]; acc1.w += al1 * (float)h1[3];
            acc0.x += al2 * (float)h2[0]; acc0.y += al2 * (float)h2[1];
            acc0.z += al2 * (float)h2[2]; acc0.w += al2 * (float)h2[3];
            acc1.x += al3 * (float)h3[0]; acc1.y += al3 * (float)h3[1];
            acc1.z += al3 * (float)h3[2]; acc1.w += al3 * (float)h3[3];
        }
        for (; j < deg; ++j) {
            int s0 = __shfl(sreg, j, 64);
            float al0 = alpha_lds[w][j * 4 + head];
            half4v h0 = *(const half4v*)(H16 + (size_t)s0 * HC + lane * 4);
            acc0.x += al0 * (float)h0[0]; acc0.y += al0 * (float)h0[1];
            acc0.z += al0 * (float)h0[2]; acc0.w += al0 * (float)h0[3];
        }
    } else {
        float m[4] = {-1e30f, -1e30f, -1e30f, -1e30f};
        float l[4] = {0.f, 0.f, 0.f, 0.f};
        for (int base = 0; base < deg; base += 64) {
            int j = base + lane;
            if (j < deg) {
                int s = csr_src[off + j];
                float4 esv = *(const float4*)(es + (size_t)s * 4);
                float e[4] = {esv.x + edv.x, esv.y + edv.y, esv.z + edv.z, esv.w + edv.w};
                #pragma unroll
                for (int h = 0; h < 4; ++h) {
                    e[h] = (e[h] > 0.f) ? e[h] : NEG * e[h];
                    float M2 = fmaxf(m[h], e[h]);
                    l[h] = l[h] * __expf(m[h] - M2) + __expf(e[h] - M2);
                    m[h] = M2;
                }
            }
        }
        #pragma unroll
        for (int msk = 1; msk < 64; msk <<= 1) {
            #pragma unroll
            for (int h = 0; h < 4; ++h) {
                float mo = __shfl_xor(m[h], msk, 64);
                float lo = __shfl_xor(l[h], msk, 64);
                float M2 = fmaxf(m[h], mo);
                l[h] = l[h] * __expf(m[h] - M2) + lo * __expf(mo - M2);
                m[h] = M2;
            }
        }
        float fm = m[head];
        float fr = 1.f / (l[head] + 1e-16f);
        float edh = ((const float*)&edv)[head];
        for (int j = 0; j < deg; ++j) {
            int s = csr_src[off + j];
            float e = es[(size_t)s * 4 + head] + edh;
            e = (e > 0.f) ? e : NEG * e;
            float alpha = __expf(e - fm) * fr;
            half4v h0 = *(const half4v*)(H16 + (size_t)s * HC + lane * 4);
            acc0.x += alpha * (float)h0[0]; acc0.y += alpha * (float)h0[1];
            acc0.z += alpha * (float)h0[2]; acc0.w += alpha * (float)h0[3];
        }
    }

    float4 b4 = *(const float4*)(bias + lane * 4);
    float4 o;
    o.x = acc0.x + acc1.x + b4.x; o.y = acc0.y + acc1.y + b4.y;
    o.z = acc0.z + acc1.z + b4.z; o.w = acc0.w + acc1.w + b4.w;
    if (do_relu) {
        o.x = fmaxf(o.x, 0.f); o.y = fmaxf(o.y, 0.f);
        o.z = fmaxf(o.z, 0.f); o.w = fmaxf(o.w, 0.f);
    }
    *(float4*)(out + (size_t)n * HC + lane * 4) = o;
}

// ---------------- launch ----------------

extern "C" void kernel_launch(void* const* d_in, const int* in_sizes, int n_in,
                              void* d_out, int out_size, void* d_ws, size_t ws_size,
                              hipStream_t stream) {
    const float* x  = (const float*)d_in[0];
    const int*   ei = (const int*)d_in[1];
    const float *W[5], *Asrc[5], *Adst[5], *Bs[5];
    for (int l = 0; l < 4; ++l) {
        W[l]    = (const float*)d_in[2 + l * 4];
        Asrc[l] = (const float*)d_in[3 + l * 4];
        Adst[l] = (const float*)d_in[4 + l * 4];
        Bs[l]   = (const float*)d_in[5 + l * 4];
    }
    W[4] = W[3]; Asrc[4] = Asrc[3]; Adst[4] = Adst[3]; Bs[4] = Bs[3];

    char* ws = (char*)d_ws;
    size_t off = 0;
    auto alloc = [&](size_t bytes) -> void* {
        void* p = ws + off;
        off += (bytes + 255) & ~(size_t)255;
        return p;
    };
    _Float16* h16  = (_Float16*)alloc((size_t)N_NODES * HC * 2);
    float* xa      = (float*)alloc((size_t)N_NODES * HC * 4);
    float* xb      = (float*)alloc((size_t)N_NODES * HC * 4);
    float* xc      = (float*)alloc((size_t)N_NODES * HC * 4);
    float* es      = (float*)alloc((size_t)N_NODES * 4 * 4);
    float* ed      = (float*)alloc((size_t)N_NODES * 4 * 4);
    int*   counts  = (int*)alloc((size_t)N_NODES * 4);
    int*   offsets = (int*)alloc((size_t)(N_NODES + 1) * 4);
    int*   cursor  = (int*)alloc((size_t)N_NODES * 4);
    int*   csr_src = (int*)alloc((size_t)ETOT * 4);
    int*   blocksums = (int*)alloc((size_t)NBLK * 4);
    _Float16 *Wth[5], *Wtl[5];
    int Ks[4] = {128, 256, 256, 256};
    for (int l = 0; l < 4; ++l) {
        Wth[l] = (_Float16*)alloc((size_t)256 * Ks[l] * 2);
        Wtl[l] = (_Float16*)alloc((size_t)256 * Ks[l] * 2);
    }
    Wth[4] = Wth[3]; Wtl[4] = Wtl[3];

    hipMemsetAsync(counts, 0, (size_t)N_NODES * 4, stream);
    count_kernel<<<(ETOT + 255) / 256, 256, 0, stream>>>(ei, counts);
    blocksum_kernel<<<NBLK, 256, 0, stream>>>(counts, blocksums);
    blockscan_kernel<<<1, 64, 0, stream>>>(blocksums);
    scatter_scan_kernel<<<NBLK, 1024, 0, stream>>>(counts, blocksums, offsets, cursor);
    fill_kernel<<<(ETOT + 255) / 256, 256, 0, stream>>>(ei, cursor, csr_src);
    for (int l = 0; l < 4; ++l)
        wsplit_kernel<<<(Ks[l] * 256 + 255) / 256, 256, 0, stream>>>(W[l], Wth[l], Wtl[l], Ks[l]);

    auto layer = [&](const float* in1, const float* in2, int K, int l, float* outp, int relu) {
        dim3 g((N_NODES + 127) / 128, 2);
        gemm_mfma_kernel<<<g, 256, 0, stream>>>(in1, in2, Wth[l], Wtl[l], h16, N_NODES, K);
        esed_kernel<<<N_NODES / 4, 256, 0, stream>>>(h16, Asrc[l], Adst[l], es, ed);
        gat_aggregate_kernel<<<N_NODES / 4, 256, 0, stream>>>(h16, es, ed, offsets, csr_src,
                                                              Bs[l], outp, relu);
    };

    float* out = (float*)d_out;
    layer(x,  nullptr, 128, 0, xa, 1);  // x1 = relu(gat(x))
    layer(xa, nullptr, 256, 1, xb, 1);  // x2 = relu(gat(x1))
    layer(xb, xa,      256, 2, xc, 1);  // x3 = relu(gat(x2+x1))
    layer(xb, xc,      256, 3, xa, 1);  // x4 = relu(gat(x2+x3))
    layer(xa, xc,      256, 4, out, 0); // x5 = gat(x4+x3), no relu
}

// Round 6
// 887.424 us; speedup vs baseline: 1.4939x; 1.0025x over previous
//
#include <hip/hip_runtime.h>
#include <hip/hip_bf16.h>

#define N_NODES 50000
#define E_EDGES 800000
#define ETOT (E_EDGES + N_NODES)
#define HC 256
#define NHEAD 4
#define CHAN 64
#define NEG 0.2f
#define NBLK ((N_NODES + 1023) / 1024)   // 49

typedef _Float16 half8 __attribute__((ext_vector_type(8)));
typedef _Float16 half4v __attribute__((ext_vector_type(4)));
typedef float float4v __attribute__((ext_vector_type(4)));

// ---------------- CSR build (once per call; shared across all 5 layers) ----------------

__global__ void count_kernel(const int* __restrict__ ei, int* __restrict__ counts) {
    int i = blockIdx.x * blockDim.x + threadIdx.x;
    if (i >= ETOT) return;
    int dst = (i < E_EDGES) ? ei[E_EDGES + i] : (i - E_EDGES);
    atomicAdd(&counts[dst], 1);
}

__global__ __launch_bounds__(256) void blocksum_kernel(const int* __restrict__ counts,
                                                       int* __restrict__ blocksums) {
    __shared__ int s[4];
    int b = blockIdx.x, tid = threadIdx.x;
    int base = b * 1024;
    int sum = 0;
    #pragma unroll
    for (int r = 0; r < 4; ++r) {
        int idx = base + r * 256 + tid;
        sum += (idx < N_NODES) ? counts[idx] : 0;
    }
    #pragma unroll
    for (int m = 1; m < 64; m <<= 1) sum += __shfl_xor(sum, m, 64);
    if ((tid & 63) == 0) s[tid >> 6] = sum;
    __syncthreads();
    if (tid == 0) blocksums[b] = s[0] + s[1] + s[2] + s[3];
}

__global__ __launch_bounds__(64) void blockscan_kernel(int* __restrict__ blocksums) {
    int tid = threadIdx.x;
    int v = (tid < NBLK) ? blocksums[tid] : 0;
    #pragma unroll
    for (int off = 1; off < 64; off <<= 1) {
        int t = __shfl_up(v, off, 64);
        if (tid >= off) v += t;
    }
    if (tid < NBLK) blocksums[tid] = v;   // inclusive
}

__global__ __launch_bounds__(1024) void scatter_scan_kernel(const int* __restrict__ counts,
                                                            const int* __restrict__ blocksums,
                                                            int* __restrict__ offsets,
                                                            int* __restrict__ cursor) {
    __shared__ int s[1024];
    int b = blockIdx.x, tid = threadIdx.x;
    int idx = b * 1024 + tid;
    int v = (idx < N_NODES) ? counts[idx] : 0;
    s[tid] = v;
    __syncthreads();
    for (int off = 1; off < 1024; off <<= 1) {
        int t = (tid >= off) ? s[tid - off] : 0;
        __syncthreads();
        s[tid] += t;
        __syncthreads();
    }
    int excl = s[tid] - v + (b > 0 ? blocksums[b - 1] : 0);
    if (idx < N_NODES) { offsets[idx] = excl; cursor[idx] = excl; }
    if (idx == N_NODES - 1) offsets[N_NODES] = excl + v;
}

__global__ void fill_kernel(const int* __restrict__ ei, int* __restrict__ cursor,
                            int* __restrict__ csr_src) {
    int i = blockIdx.x * blockDim.x + threadIdx.x;
    if (i >= ETOT) return;
    int src, dst;
    if (i < E_EDGES) { src = ei[i]; dst = ei[E_EDGES + i]; }
    else             { src = i - E_EDGES; dst = src; }
    int pos = atomicAdd(&cursor[dst], 1);
    csr_src[pos] = src;
}

// ---------------- weight pre-split: W[K][256] fp32 -> Wt_h/Wt_l [n][k] f16 ----------------

__global__ void wsplit_kernel(const float* __restrict__ W, _Float16* __restrict__ Wth,
                              _Float16* __restrict__ Wtl, int K) {
    int id = blockIdx.x * 256 + threadIdx.x;
    if (id >= K * 256) return;
    int n = id & 255, k = id >> 8;
    float w = W[(size_t)k * 256 + n];
    _Float16 h = (_Float16)w;
    _Float16 l = (_Float16)(w - (float)h);
    Wth[(size_t)n * K + k] = h;
    Wtl[(size_t)n * K + k] = l;
}

// ---------------- f16-split MFMA GEMM: H16[M,256] = f16((A1 (+A2)) @ W[K,256]) ----------------
// BM=64, BN=256 (full width => A read exactly once), BK=32, 256 thr / 4 waves.
// Wave w owns the 64-col quarter [w*64, w*64+64). 3-MFMA error-compensated chain.

#define LDK 40

__global__ __launch_bounds__(256) void gemm_mfma_kernel(
        const float* __restrict__ A1, const float* __restrict__ A2,
        const _Float16* __restrict__ Wth, const _Float16* __restrict__ Wtl,
        _Float16* __restrict__ H16, int M, int K) {
    __shared__ _Float16 Ah[64][LDK];
    __shared__ _Float16 Al[64][LDK];
    __shared__ _Float16 Bh[256][LDK];
    __shared__ _Float16 Bl[256][LDK];

    int tid = threadIdx.x;
    int m0 = blockIdx.x * 64;
    int w = tid >> 6, lane = tid & 63;
    int rn = w * 64;
    int fr = lane & 15;
    int fk = (lane >> 4) * 8;

    int ar = tid >> 3;            // 0..31 (A: 8 thr/row)
    int ak = (tid & 7) * 4;       // 0..28
    int wr = tid >> 2;            // 0..63 (B: 4 thr/row)
    int wk = (tid & 3) * 8;       // 0,8,16,24

    float4v acc[4][4];
    #pragma unroll
    for (int i = 0; i < 4; ++i)
        #pragma unroll
        for (int j = 0; j < 4; ++j)
            acc[i][j] = (float4v){0.f, 0.f, 0.f, 0.f};

    for (int k0 = 0; k0 < K; k0 += 32) {
        __syncthreads();
        // ---- stage A (+residual) as f16 hi/lo: 64 rows x 32 cols ----
        #pragma unroll
        for (int g = 0; g < 2; ++g) {
            int r = g * 32 + ar;
            int row = m0 + r;
            float4 v = make_float4(0.f, 0.f, 0.f, 0.f);
            if (row < M) {
                v = *(const float4*)(A1 + (size_t)row * K + k0 + ak);
                if (A2) {
                    float4 u = *(const float4*)(A2 + (size_t)row * K + k0 + ak);
                    v.x += u.x; v.y += u.y; v.z += u.z; v.w += u.w;
                }
            }
            half4v hv = {(_Float16)v.x, (_Float16)v.y, (_Float16)v.z, (_Float16)v.w};
            half4v lv = {(_Float16)(v.x - (float)hv[0]), (_Float16)(v.y - (float)hv[1]),
                         (_Float16)(v.z - (float)hv[2]), (_Float16)(v.w - (float)hv[3])};
            *(half4v*)&Ah[r][ak] = hv;
            *(half4v*)&Al[r][ak] = lv;
        }
        // ---- stage B: 256 rows x 32 k ----
        #pragma unroll
        for (int g = 0; g < 4; ++g) {
            int r = g * 64 + wr;
            *(half8*)&Bh[r][wk] = *(const half8*)(Wth + (size_t)r * K + k0 + wk);
            *(half8*)&Bl[r][wk] = *(const half8*)(Wtl + (size_t)r * K + k0 + wk);
        }
        __syncthreads();
        // ---- fragments ----
        half8 afh[4], afl[4], bfh[4], bfl[4];
        #pragma unroll
        for (int t = 0; t < 4; ++t) {
            afh[t] = *(const half8*)&Ah[t * 16 + fr][fk];
            afl[t] = *(const half8*)&Al[t * 16 + fr][fk];
            bfh[t] = *(const half8*)&Bh[rn + t * 16 + fr][fk];
            bfl[t] = *(const half8*)&Bl[rn + t * 16 + fr][fk];
        }
        #pragma unroll
        for (int tm = 0; tm < 4; ++tm)
            #pragma unroll
            for (int tn = 0; tn < 4; ++tn) {
                float4v c = acc[tm][tn];
                c = __builtin_amdgcn_mfma_f32_16x16x32_f16(afl[tm], bfh[tn], c, 0, 0, 0);
                c = __builtin_amdgcn_mfma_f32_16x16x32_f16(afh[tm], bfl[tn], c, 0, 0, 0);
                c = __builtin_amdgcn_mfma_f32_16x16x32_f16(afh[tm], bfh[tn], c, 0, 0, 0);
                acc[tm][tn] = c;
            }
    }
    // ---- epilogue: C/D layout col=lane&15, row=(lane>>4)*4+i ----
    #pragma unroll
    for (int tm = 0; tm < 4; ++tm) {
        int rbase = m0 + tm * 16 + (lane >> 4) * 4;
        #pragma unroll
        for (int i = 0; i < 4; ++i) {
            int row = rbase + i;
            if (row < M) {
                #pragma unroll
                for (int tn = 0; tn < 4; ++tn)
                    H16[(size_t)row * HC + rn + tn * 16 + fr] = (_Float16)acc[tm][tn][i];
            }
        }
    }
}

// ---------------- per-node attention logits (f16 H) ----------------

__global__ __launch_bounds__(256) void esed_kernel(const _Float16* __restrict__ H16,
                                                   const float* __restrict__ a_src,
                                                   const float* __restrict__ a_dst,
                                                   float* __restrict__ es, float* __restrict__ ed) {
    int tid = threadIdx.x;
    int lane = tid & 63;
    int node = blockIdx.x * 4 + (tid >> 6);
    int head = lane >> 4;
    int cc = (lane & 15) * 4;
    half4v hv = *(const half4v*)(H16 + (size_t)node * HC + lane * 4);
    float4 h4 = make_float4((float)hv[0], (float)hv[1], (float)hv[2], (float)hv[3]);
    float4 as = *(const float4*)(a_src + head * CHAN + cc);
    float4 ad = *(const float4*)(a_dst + head * CHAN + cc);
    float ps = h4.x * as.x + h4.y * as.y + h4.z * as.z + h4.w * as.w;
    float pd = h4.x * ad.x + h4.y * ad.y + h4.z * ad.z + h4.w * ad.w;
    #pragma unroll
    for (int m = 1; m < 16; m <<= 1) {
        ps += __shfl_xor(ps, m, 64);
        pd += __shfl_xor(pd, m, 64);
    }
    if ((lane & 15) == 0) {
        es[node * NHEAD + head] = ps;
        ed[node * NHEAD + head] = pd;
    }
}

// ---------------- fused edge-softmax + aggregation: ONE WAVE per dst node ----------------
// Fast path: softmax with lane=edge, then gather with 2 edges per wave
// (32 lanes x half8 = one 512B row each), combined via shfl_xor(32).

__global__ __launch_bounds__(256) void gat_aggregate_kernel(
        const _Float16* __restrict__ H16, const float* __restrict__ es, const float* __restrict__ ed,
        const int* __restrict__ offsets, const int* __restrict__ csr_src,
        const float* __restrict__ bias, float* __restrict__ out, int do_relu) {
    __shared__ float alpha_lds[4][256];
    int tid = threadIdx.x;
    int w = tid >> 6, lane = tid & 63;
    int n = blockIdx.x * 4 + w;
    int off = offsets[n];
    int deg = offsets[n + 1] - off;
    float4 edv = *(const float4*)(ed + (size_t)n * 4);

    if (deg <= 64) {
        // --- softmax: lane = edge ---
        int sreg = 0;
        float4 e4 = make_float4(-1e30f, -1e30f, -1e30f, -1e30f);
        if (lane < deg) {
            sreg = csr_src[off + lane];
            float4 esv = *(const float4*)(es + (size_t)sreg * 4);
            e4.x = esv.x + edv.x; e4.y = esv.y + edv.y;
            e4.z = esv.z + edv.z; e4.w = esv.w + edv.w;
            e4.x = (e4.x > 0.f) ? e4.x : NEG * e4.x;
            e4.y = (e4.y > 0.f) ? e4.y : NEG * e4.y;
            e4.z = (e4.z > 0.f) ? e4.z : NEG * e4.z;
            e4.w = (e4.w > 0.f) ? e4.w : NEG * e4.w;
        }
        float4 m4 = e4;
        #pragma unroll
        for (int msk = 1; msk < 64; msk <<= 1) {
            m4.x = fmaxf(m4.x, __shfl_xor(m4.x, msk, 64));
            m4.y = fmaxf(m4.y, __shfl_xor(m4.y, msk, 64));
            m4.z = fmaxf(m4.z, __shfl_xor(m4.z, msk, 64));
            m4.w = fmaxf(m4.w, __shfl_xor(m4.w, msk, 64));
        }
        float4 ex4 = make_float4(0.f, 0.f, 0.f, 0.f);
        if (lane < deg) {
            ex4.x = __expf(e4.x - m4.x); ex4.y = __expf(e4.y - m4.y);
            ex4.z = __expf(e4.z - m4.z); ex4.w = __expf(e4.w - m4.w);
        }
        float4 l4 = ex4;
        #pragma unroll
        for (int msk = 1; msk < 64; msk <<= 1) {
            l4.x += __shfl_xor(l4.x, msk, 64);
            l4.y += __shfl_xor(l4.y, msk, 64);
            l4.z += __shfl_xor(l4.z, msk, 64);
            l4.w += __shfl_xor(l4.w, msk, 64);
        }
        float4 a4;
        a4.x = ex4.x / (l4.x + 1e-16f);
        a4.y = ex4.y / (l4.y + 1e-16f);
        a4.z = ex4.z / (l4.z + 1e-16f);
        a4.w = ex4.w / (l4.w + 1e-16f);
        *(float4*)&alpha_lds[w][lane * 4] = a4;   // same-wave write+read: no barrier

        // --- gather: 2 edges per wave; 32 lanes x 8 channels (16B loads) ---
        int hl = lane & 31, side = lane >> 5;
        int hd = hl >> 3;                       // head of this lane's 8 channels
        float av[8] = {0.f, 0.f, 0.f, 0.f, 0.f, 0.f, 0.f, 0.f};
        #pragma unroll 2
        for (int j = side; j < deg; j += 2) {
            int s = __shfl(sreg, j, 64);
            float al = alpha_lds[w][j * 4 + hd];
            half8 hv = *(const half8*)(H16 + (size_t)s * HC + hl * 8);
            #pragma unroll
            for (int c = 0; c < 8; ++c) av[c] += al * (float)hv[c];
        }
        #pragma unroll
        for (int c = 0; c < 8; ++c) av[c] += __shfl_xor(av[c], 32, 64);
        if (side == 0) {
            float4 b0 = *(const float4*)(bias + hl * 8);
            float4 b1 = *(const float4*)(bias + hl * 8 + 4);
            float4 o0 = make_float4(av[0] + b0.x, av[1] + b0.y, av[2] + b0.z, av[3] + b0.w);
            float4 o1 = make_float4(av[4] + b1.x, av[5] + b1.y, av[6] + b1.z, av[7] + b1.w);
            if (do_relu) {
                o0.x = fmaxf(o0.x, 0.f); o0.y = fmaxf(o0.y, 0.f);
                o0.z = fmaxf(o0.z, 0.f); o0.w = fmaxf(o0.w, 0.f);
                o1.x = fmaxf(o1.x, 0.f); o1.y = fmaxf(o1.y, 0.f);
                o1.z = fmaxf(o1.z, 0.f); o1.w = fmaxf(o1.w, 0.f);
            }
            *(float4*)(out + (size_t)n * HC + hl * 8) = o0;
            *(float4*)(out + (size_t)n * HC + hl * 8 + 4) = o1;
        }
        return;
    }

    // --- generic fallback (deg > 64): 4 channels/lane ---
    int head = lane >> 4;
    float4 acc0 = make_float4(0.f, 0.f, 0.f, 0.f);
    float m[4] = {-1e30f, -1e30f, -1e30f, -1e30f};
    float l[4] = {0.f, 0.f, 0.f, 0.f};
    for (int base = 0; base < deg; base += 64) {
        int j = base + lane;
        if (j < deg) {
            int s = csr_src[off + j];
            float4 esv = *(const float4*)(es + (size_t)s * 4);
            float e[4] = {esv.x + edv.x, esv.y + edv.y, esv.z + edv.z, esv.w + edv.w};
            #pragma unroll
            for (int h = 0; h < 4; ++h) {
                e[h] = (e[h] > 0.f) ? e[h] : NEG * e[h];
                float M2 = fmaxf(m[h], e[h]);
                l[h] = l[h] * __expf(m[h] - M2) + __expf(e[h] - M2);
                m[h] = M2;
            }
        }
    }
    #pragma unroll
    for (int msk = 1; msk < 64; msk <<= 1) {
        #pragma unroll
        for (int h = 0; h < 4; ++h) {
            float mo = __shfl_xor(m[h], msk, 64);
            float lo = __shfl_xor(l[h], msk, 64);
            float M2 = fmaxf(m[h], mo);
            l[h] = l[h] * __expf(m[h] - M2) + lo * __expf(mo - M2);
            m[h] = M2;
        }
    }
    float fm = m[head];
    float fr = 1.f / (l[head] + 1e-16f);
    float edh = ((const float*)&edv)[head];
    for (int j = 0; j < deg; ++j) {
        int s = csr_src[off + j];
        float e = es[(size_t)s * 4 + head] + edh;
        e = (e > 0.f) ? e : NEG * e;
        float alpha = __expf(e - fm) * fr;
        half4v h0 = *(const half4v*)(H16 + (size_t)s * HC + lane * 4);
        acc0.x += alpha * (float)h0[0]; acc0.y += alpha * (float)h0[1];
        acc0.z += alpha * (float)h0[2]; acc0.w += alpha * (float)h0[3];
    }
    float4 b4 = *(const float4*)(bias + lane * 4);
    float4 o;
    o.x = acc0.x + b4.x; o.y = acc0.y + b4.y;
    o.z = acc0.z + b4.z; o.w = acc0.w + b4.w;
    if (do_relu) {
        o.x = fmaxf(o.x, 0.f); o.y = fmaxf(o.y, 0.f);
        o.z = fmaxf(o.z, 0.f); o.w = fmaxf(o.w, 0.f);
    }
    *(float4*)(out + (size_t)n * HC + lane * 4) = o;
}

// ---------------- launch ----------------

extern "C" void kernel_launch(void* const* d_in, const int* in_sizes, int n_in,
                              void* d_out, int out_size, void* d_ws, size_t ws_size,
                              hipStream_t stream) {
    const float* x  = (const float*)d_in[0];
    const int*   ei = (const int*)d_in[1];
    const float *W[5], *Asrc[5], *Adst[5], *Bs[5];
    for (int l = 0; l < 4; ++l) {
        W[l]    = (const float*)d_in[2 + l * 4];
        Asrc[l] = (const float*)d_in[3 + l * 4];
        Adst[l] = (const float*)d_in[4 + l * 4];
        Bs[l]   = (const float*)d_in[5 + l * 4];
    }
    W[4] = W[3]; Asrc[4] = Asrc[3]; Adst[4] = Adst[3]; Bs[4] = Bs[3];

    char* ws = (char*)d_ws;
    size_t off = 0;
    auto alloc = [&](size_t bytes) -> void* {
        void* p = ws + off;
        off += (bytes + 255) & ~(size_t)255;
        return p;
    };
    _Float16* h16  = (_Float16*)alloc((size_t)N_NODES * HC * 2);
    float* xa      = (float*)alloc((size_t)N_NODES * HC * 4);
    float* xb      = (float*)alloc((size_t)N_NODES * HC * 4);
    float* xc      = (float*)alloc((size_t)N_NODES * HC * 4);
    float* es      = (float*)alloc((size_t)N_NODES * 4 * 4);
    float* ed      = (float*)alloc((size_t)N_NODES * 4 * 4);
    int*   counts  = (int*)alloc((size_t)N_NODES * 4);
    int*   offsets = (int*)alloc((size_t)(N_NODES + 1) * 4);
    int*   cursor  = (int*)alloc((size_t)N_NODES * 4);
    int*   csr_src = (int*)alloc((size_t)ETOT * 4);
    int*   blocksums = (int*)alloc((size_t)NBLK * 4);
    _Float16 *Wth[5], *Wtl[5];
    int Ks[4] = {128, 256, 256, 256};
    for (int l = 0; l < 4; ++l) {
        Wth[l] = (_Float16*)alloc((size_t)256 * Ks[l] * 2);
        Wtl[l] = (_Float16*)alloc((size_t)256 * Ks[l] * 2);
    }
    Wth[4] = Wth[3]; Wtl[4] = Wtl[3];

    hipMemsetAsync(counts, 0, (size_t)N_NODES * 4, stream);
    count_kernel<<<(ETOT + 255) / 256, 256, 0, stream>>>(ei, counts);
    blocksum_kernel<<<NBLK, 256, 0, stream>>>(counts, blocksums);
    blockscan_kernel<<<1, 64, 0, stream>>>(blocksums);
    scatter_scan_kernel<<<NBLK, 1024, 0, stream>>>(counts, blocksums, offsets, cursor);
    fill_kernel<<<(ETOT + 255) / 256, 256, 0, stream>>>(ei, cursor, csr_src);
    for (int l = 0; l < 4; ++l)
        wsplit_kernel<<<(Ks[l] * 256 + 255) / 256, 256, 0, stream>>>(W[l], Wth[l], Wtl[l], Ks[l]);

    auto layer = [&](const float* in1, const float* in2, int K, int l, float* outp, int relu) {
        gemm_mfma_kernel<<<(N_NODES + 63) / 64, 256, 0, stream>>>(in1, in2, Wth[l], Wtl[l],
                                                                  h16, N_NODES, K);
        esed_kernel<<<N_NODES / 4, 256, 0, stream>>>(h16, Asrc[l], Adst[l], es, ed);
        gat_aggregate_kernel<<<N_NODES / 4, 256, 0, stream>>>(h16, es, ed, offsets, csr_src,
                                                              Bs[l], outp, relu);
    };

    float* out = (float*)d_out;
    layer(x,  nullptr, 128, 0, xa, 1);  // x1 = relu(gat(x))
    layer(xa, nullptr, 256, 1, xb, 1);  // x2 = relu(gat(x1))
    layer(xb, xa,      256, 2, xc, 1);  // x3 = relu(gat(x2+x1))
    layer(xb, xc,      256, 3, xa, 1);  // x4 = relu(gat(x2+x3))
    layer(xa, xc,      256, 4, out, 0); // x5 = gat(x4+x3), no relu
}

// Round 7
// 811.230 us; speedup vs baseline: 1.6342x; 1.0939x over previous
//
#include <hip/hip_runtime.h>
#include <hip/hip_bf16.h>

#define N_NODES 50000
#define E_EDGES 800000
#define ETOT (E_EDGES + N_NODES)
#define HC 256
#define NHEAD 4
#define CHAN 64
#define NEG 0.2f
#define NBLK ((N_NODES + 1023) / 1024)   // 49

typedef _Float16 half8 __attribute__((ext_vector_type(8)));
typedef _Float16 half4v __attribute__((ext_vector_type(4)));
typedef float float4v __attribute__((ext_vector_type(4)));

// ---------------- CSR build (once per call; shared across all 5 layers) ----------------

__global__ void count_kernel(const int* __restrict__ ei, int* __restrict__ counts) {
    int i = blockIdx.x * blockDim.x + threadIdx.x;
    if (i >= ETOT) return;
    int dst = (i < E_EDGES) ? ei[E_EDGES + i] : (i - E_EDGES);
    atomicAdd(&counts[dst], 1);
}

__global__ __launch_bounds__(256) void blocksum_kernel(const int* __restrict__ counts,
                                                       int* __restrict__ blocksums) {
    __shared__ int s[4];
    int b = blockIdx.x, tid = threadIdx.x;
    int base = b * 1024;
    int sum = 0;
    #pragma unroll
    for (int r = 0; r < 4; ++r) {
        int idx = base + r * 256 + tid;
        sum += (idx < N_NODES) ? counts[idx] : 0;
    }
    #pragma unroll
    for (int m = 1; m < 64; m <<= 1) sum += __shfl_xor(sum, m, 64);
    if ((tid & 63) == 0) s[tid >> 6] = sum;
    __syncthreads();
    if (tid == 0) blocksums[b] = s[0] + s[1] + s[2] + s[3];
}

__global__ __launch_bounds__(64) void blockscan_kernel(int* __restrict__ blocksums) {
    int tid = threadIdx.x;
    int v = (tid < NBLK) ? blocksums[tid] : 0;
    #pragma unroll
    for (int off = 1; off < 64; off <<= 1) {
        int t = __shfl_up(v, off, 64);
        if (tid >= off) v += t;
    }
    if (tid < NBLK) blocksums[tid] = v;   // inclusive
}

__global__ __launch_bounds__(1024) void scatter_scan_kernel(const int* __restrict__ counts,
                                                            const int* __restrict__ blocksums,
                                                            int* __restrict__ offsets,
                                                            int* __restrict__ cursor) {
    __shared__ int s[1024];
    int b = blockIdx.x, tid = threadIdx.x;
    int idx = b * 1024 + tid;
    int v = (idx < N_NODES) ? counts[idx] : 0;
    s[tid] = v;
    __syncthreads();
    for (int off = 1; off < 1024; off <<= 1) {
        int t = (tid >= off) ? s[tid - off] : 0;
        __syncthreads();
        s[tid] += t;
        __syncthreads();
    }
    int excl = s[tid] - v + (b > 0 ? blocksums[b - 1] : 0);
    if (idx < N_NODES) { offsets[idx] = excl; cursor[idx] = excl; }
    if (idx == N_NODES - 1) offsets[N_NODES] = excl + v;
}

__global__ void fill_kernel(const int* __restrict__ ei, int* __restrict__ cursor,
                            int* __restrict__ csr_src) {
    int i = blockIdx.x * blockDim.x + threadIdx.x;
    if (i >= ETOT) return;
    int src, dst;
    if (i < E_EDGES) { src = ei[i]; dst = ei[E_EDGES + i]; }
    else             { src = i - E_EDGES; dst = src; }
    int pos = atomicAdd(&cursor[dst], 1);
    csr_src[pos] = src;
}

// ---------------- weight pre-split: W[K][256] fp32 -> Wt_h/Wt_l [n][k] f16 ----------------

__global__ void wsplit_kernel(const float* __restrict__ W, _Float16* __restrict__ Wth,
                              _Float16* __restrict__ Wtl, int K) {
    int id = blockIdx.x * 256 + threadIdx.x;
    if (id >= K * 256) return;
    int n = id & 255, k = id >> 8;
    float w = W[(size_t)k * 256 + n];
    _Float16 h = (_Float16)w;
    _Float16 l = (_Float16)(w - (float)h);
    Wth[(size_t)n * K + k] = h;
    Wtl[(size_t)n * K + k] = l;
}

// ---------------- f16-split MFMA GEMM + fused es/ed epilogue ----------------
// BM=64, BN=256 (A read once), BK=32, 256 thr / 4 waves; wave w owns head-w's
// 64-col slice. Register prefetch of next tile overlaps global loads with MFMA.
// Epilogue: H16 write + es/ed = <h, a_src/dst> via in-register dot + 16-lane reduce.

#define LDK 40

__global__ __launch_bounds__(256) void gemm_mfma_kernel(
        const float* __restrict__ A1, const float* __restrict__ A2,
        const _Float16* __restrict__ Wth, const _Float16* __restrict__ Wtl,
        const float* __restrict__ a_src, const float* __restrict__ a_dst,
        _Float16* __restrict__ H16, float* __restrict__ es, float* __restrict__ ed,
        int M, int K) {
    __shared__ _Float16 Ah[64][LDK];
    __shared__ _Float16 Al[64][LDK];
    __shared__ _Float16 Bh[256][LDK];
    __shared__ _Float16 Bl[256][LDK];

    int tid = threadIdx.x;
    int m0 = blockIdx.x * 64;
    int w = tid >> 6, lane = tid & 63;
    int rn = w * 64;
    int fr = lane & 15;
    int q  = lane >> 4;
    int fk = q * 8;

    int ar = tid >> 3;            // 0..31 (A: 8 thr/row)
    int ak = (tid & 7) * 4;       // 0..28
    int wr = tid >> 2;            // 0..63 (B: 4 thr/row)
    int wk = (tid & 3) * 8;       // 0,8,16,24

    float4v acc[4][4];
    #pragma unroll
    for (int i = 0; i < 4; ++i)
        #pragma unroll
        for (int j = 0; j < 4; ++j)
            acc[i][j] = (float4v){0.f, 0.f, 0.f, 0.f};

    bool has2 = (A2 != nullptr);
    float4 pa1[2], pa2[2];
    half8 pbh[4], pbl[4];

    auto load_tile = [&](int k0) {
        #pragma unroll
        for (int g = 0; g < 2; ++g) {
            int row = m0 + g * 32 + ar;
            pa1[g] = make_float4(0.f, 0.f, 0.f, 0.f);
            pa2[g] = make_float4(0.f, 0.f, 0.f, 0.f);
            if (row < M) {
                pa1[g] = *(const float4*)(A1 + (size_t)row * K + k0 + ak);
                if (has2) pa2[g] = *(const float4*)(A2 + (size_t)row * K + k0 + ak);
            }
        }
        #pragma unroll
        for (int g = 0; g < 4; ++g) {
            int r = g * 64 + wr;
            pbh[g] = *(const half8*)(Wth + (size_t)r * K + k0 + wk);
            pbl[g] = *(const half8*)(Wtl + (size_t)r * K + k0 + wk);
        }
    };

    load_tile(0);
    for (int k0 = 0; k0 < K; k0 += 32) {
        // ---- store staged regs to LDS (A: f16 hi/lo split at store time) ----
        #pragma unroll
        for (int g = 0; g < 2; ++g) {
            int r = g * 32 + ar;
            float4 v;
            v.x = pa1[g].x + pa2[g].x; v.y = pa1[g].y + pa2[g].y;
            v.z = pa1[g].z + pa2[g].z; v.w = pa1[g].w + pa2[g].w;
            half4v hv = {(_Float16)v.x, (_Float16)v.y, (_Float16)v.z, (_Float16)v.w};
            half4v lv = {(_Float16)(v.x - (float)hv[0]), (_Float16)(v.y - (float)hv[1]),
                         (_Float16)(v.z - (float)hv[2]), (_Float16)(v.w - (float)hv[3])};
            *(half4v*)&Ah[r][ak] = hv;
            *(half4v*)&Al[r][ak] = lv;
        }
        #pragma unroll
        for (int g = 0; g < 4; ++g) {
            int r = g * 64 + wr;
            *(half8*)&Bh[r][wk] = pbh[g];
            *(half8*)&Bl[r][wk] = pbl[g];
        }
        __syncthreads();
        // ---- prefetch next tile: loads stay in flight across the MFMA phase ----
        if (k0 + 32 < K) load_tile(k0 + 32);
        // ---- fragments + MFMA ----
        half8 afh[4], afl[4], bfh[4], bfl[4];
        #pragma unroll
        for (int t = 0; t < 4; ++t) {
            afh[t] = *(const half8*)&Ah[t * 16 + fr][fk];
            afl[t] = *(const half8*)&Al[t * 16 + fr][fk];
            bfh[t] = *(const half8*)&Bh[rn + t * 16 + fr][fk];
            bfl[t] = *(const half8*)&Bl[rn + t * 16 + fr][fk];
        }
        #pragma unroll
        for (int tm = 0; tm < 4; ++tm)
            #pragma unroll
            for (int tn = 0; tn < 4; ++tn) {
                float4v c = acc[tm][tn];
                c = __builtin_amdgcn_mfma_f32_16x16x32_f16(afl[tm], bfh[tn], c, 0, 0, 0);
                c = __builtin_amdgcn_mfma_f32_16x16x32_f16(afh[tm], bfl[tn], c, 0, 0, 0);
                c = __builtin_amdgcn_mfma_f32_16x16x32_f16(afh[tm], bfh[tn], c, 0, 0, 0);
                acc[tm][tn] = c;
            }
        __syncthreads();
    }

    // ---- epilogue: H16 write + fused es/ed ----
    // C/D layout: row = tm*16 + q*4 + i, col = rn + tn*16 + fr. Wave w == head w.
    float asv[4], adv[4];
    #pragma unroll
    for (int tn = 0; tn < 4; ++tn) {
        asv[tn] = a_src[w * CHAN + tn * 16 + fr];
        adv[tn] = a_dst[w * CHAN + tn * 16 + fr];
    }
    #pragma unroll
    for (int tm = 0; tm < 4; ++tm) {
        #pragma unroll
        for (int i = 0; i < 4; ++i) {
            int row = m0 + tm * 16 + q * 4 + i;
            float ps = 0.f, pd = 0.f;
            #pragma unroll
            for (int tn = 0; tn < 4; ++tn) {
                float hv = acc[tm][tn][i];
                ps += hv * asv[tn];
                pd += hv * adv[tn];
                if (row < M)
                    H16[(size_t)row * HC + rn + tn * 16 + fr] = (_Float16)hv;
            }
            // reduce over fr (16 lanes; masks <16 keep q fixed)
            #pragma unroll
            for (int msk = 1; msk < 16; msk <<= 1) {
                ps += __shfl_xor(ps, msk, 64);
                pd += __shfl_xor(pd, msk, 64);
            }
            if (fr == 0 && row < M) {
                es[row * NHEAD + w] = ps;
                ed[row * NHEAD + w] = pd;
            }
        }
    }
}

// ---------------- fused edge-softmax + aggregation: ONE WAVE per dst node ----------------
// Fast path: softmax with lane=edge, then gather with 2 edges per wave
// (32 lanes x half8 = one 512B row each), combined via shfl_xor(32).

__global__ __launch_bounds__(256) void gat_aggregate_kernel(
        const _Float16* __restrict__ H16, const float* __restrict__ es, const float* __restrict__ ed,
        const int* __restrict__ offsets, const int* __restrict__ csr_src,
        const float* __restrict__ bias, float* __restrict__ out, int do_relu) {
    __shared__ float alpha_lds[4][256];
    int tid = threadIdx.x;
    int w = tid >> 6, lane = tid & 63;
    int n = blockIdx.x * 4 + w;
    int off = offsets[n];
    int deg = offsets[n + 1] - off;
    float4 edv = *(const float4*)(ed + (size_t)n * 4);

    if (deg <= 64) {
        // --- softmax: lane = edge ---
        int sreg = 0;
        float4 e4 = make_float4(-1e30f, -1e30f, -1e30f, -1e30f);
        if (lane < deg) {
            sreg = csr_src[off + lane];
            float4 esv = *(const float4*)(es + (size_t)sreg * 4);
            e4.x = esv.x + edv.x; e4.y = esv.y + edv.y;
            e4.z = esv.z + edv.z; e4.w = esv.w + edv.w;
            e4.x = (e4.x > 0.f) ? e4.x : NEG * e4.x;
            e4.y = (e4.y > 0.f) ? e4.y : NEG * e4.y;
            e4.z = (e4.z > 0.f) ? e4.z : NEG * e4.z;
            e4.w = (e4.w > 0.f) ? e4.w : NEG * e4.w;
        }
        float4 m4 = e4;
        #pragma unroll
        for (int msk = 1; msk < 64; msk <<= 1) {
            m4.x = fmaxf(m4.x, __shfl_xor(m4.x, msk, 64));
            m4.y = fmaxf(m4.y, __shfl_xor(m4.y, msk, 64));
            m4.z = fmaxf(m4.z, __shfl_xor(m4.z, msk, 64));
            m4.w = fmaxf(m4.w, __shfl_xor(m4.w, msk, 64));
        }
        float4 ex4 = make_float4(0.f, 0.f, 0.f, 0.f);
        if (lane < deg) {
            ex4.x = __expf(e4.x - m4.x); ex4.y = __expf(e4.y - m4.y);
            ex4.z = __expf(e4.z - m4.z); ex4.w = __expf(e4.w - m4.w);
        }
        float4 l4 = ex4;
        #pragma unroll
        for (int msk = 1; msk < 64; msk <<= 1) {
            l4.x += __shfl_xor(l4.x, msk, 64);
            l4.y += __shfl_xor(l4.y, msk, 64);
            l4.z += __shfl_xor(l4.z, msk, 64);
            l4.w += __shfl_xor(l4.w, msk, 64);
        }
        float4 a4;
        a4.x = ex4.x / (l4.x + 1e-16f);
        a4.y = ex4.y / (l4.y + 1e-16f);
        a4.z = ex4.z / (l4.z + 1e-16f);
        a4.w = ex4.w / (l4.w + 1e-16f);
        *(float4*)&alpha_lds[w][lane * 4] = a4;   // same-wave write+read: no barrier

        // --- gather: 2 edges per wave; 32 lanes x 8 channels (16B loads) ---
        int hl = lane & 31, side = lane >> 5;
        int hd = hl >> 3;
        float av[8] = {0.f, 0.f, 0.f, 0.f, 0.f, 0.f, 0.f, 0.f};
        #pragma unroll 2
        for (int j = side; j < deg; j += 2) {
            int s = __shfl(sreg, j, 64);
            float al = alpha_lds[w][j * 4 + hd];
            half8 hv = *(const half8*)(H16 + (size_t)s * HC + hl * 8);
            #pragma unroll
            for (int c = 0; c < 8; ++c) av[c] += al * (float)hv[c];
        }
        #pragma unroll
        for (int c = 0; c < 8; ++c) av[c] += __shfl_xor(av[c], 32, 64);
        if (side == 0) {
            float4 b0 = *(const float4*)(bias + hl * 8);
            float4 b1 = *(const float4*)(bias + hl * 8 + 4);
            float4 o0 = make_float4(av[0] + b0.x, av[1] + b0.y, av[2] + b0.z, av[3] + b0.w);
            float4 o1 = make_float4(av[4] + b1.x, av[5] + b1.y, av[6] + b1.z, av[7] + b1.w);
            if (do_relu) {
                o0.x = fmaxf(o0.x, 0.f); o0.y = fmaxf(o0.y, 0.f);
                o0.z = fmaxf(o0.z, 0.f); o0.w = fmaxf(o0.w, 0.f);
                o1.x = fmaxf(o1.x, 0.f); o1.y = fmaxf(o1.y, 0.f);
                o1.z = fmaxf(o1.z, 0.f); o1.w = fmaxf(o1.w, 0.f);
            }
            *(float4*)(out + (size_t)n * HC + hl * 8) = o0;
            *(float4*)(out + (size_t)n * HC + hl * 8 + 4) = o1;
        }
        return;
    }

    // --- generic fallback (deg > 64): 4 channels/lane ---
    int head = lane >> 4;
    float4 acc0 = make_float4(0.f, 0.f, 0.f, 0.f);
    float m[4] = {-1e30f, -1e30f, -1e30f, -1e30f};
    float l[4] = {0.f, 0.f, 0.f, 0.f};
    for (int base = 0; base < deg; base += 64) {
        int j = base + lane;
        if (j < deg) {
            int s = csr_src[off + j];
            float4 esv = *(const float4*)(es + (size_t)s * 4);
            float e[4] = {esv.x + edv.x, esv.y + edv.y, esv.z + edv.z, esv.w + edv.w};
            #pragma unroll
            for (int h = 0; h < 4; ++h) {
                e[h] = (e[h] > 0.f) ? e[h] : NEG * e[h];
                float M2 = fmaxf(m[h], e[h]);
                l[h] = l[h] * __expf(m[h] - M2) + __expf(e[h] - M2);
                m[h] = M2;
            }
        }
    }
    #pragma unroll
    for (int msk = 1; msk < 64; msk <<= 1) {
        #pragma unroll
        for (int h = 0; h < 4; ++h) {
            float mo = __shfl_xor(m[h], msk, 64);
            float lo = __shfl_xor(l[h], msk, 64);
            float M2 = fmaxf(m[h], mo);
            l[h] = l[h] * __expf(m[h] - M2) + lo * __expf(mo - M2);
            m[h] = M2;
        }
    }
    float fm = m[head];
    float fr2 = 1.f / (l[head] + 1e-16f);
    float edh = ((const float*)&edv)[head];
    for (int j = 0; j < deg; ++j) {
        int s = csr_src[off + j];
        float e = es[(size_t)s * 4 + head] + edh;
        e = (e > 0.f) ? e : NEG * e;
        float alpha = __expf(e - fm) * fr2;
        half4v h0 = *(const half4v*)(H16 + (size_t)s * HC + lane * 4);
        acc0.x += alpha * (float)h0[0]; acc0.y += alpha * (float)h0[1];
        acc0.z += alpha * (float)h0[2]; acc0.w += alpha * (float)h0[3];
    }
    float4 b4 = *(const float4*)(bias + lane * 4);
    float4 o;
    o.x = acc0.x + b4.x; o.y = acc0.y + b4.y;
    o.z = acc0.z + b4.z; o.w = acc0.w + b4.w;
    if (do_relu) {
        o.x = fmaxf(o.x, 0.f); o.y = fmaxf(o.y, 0.f);
        o.z = fmaxf(o.z, 0.f); o.w = fmaxf(o.w, 0.f);
    }
    *(float4*)(out + (size_t)n * HC + lane * 4) = o;
}

// ---------------- launch ----------------

extern "C" void kernel_launch(void* const* d_in, const int* in_sizes, int n_in,
                              void* d_out, int out_size, void* d_ws, size_t ws_size,
                              hipStream_t stream) {
    const float* x  = (const float*)d_in[0];
    const int*   ei = (const int*)d_in[1];
    const float *W[5], *Asrc[5], *Adst[5], *Bs[5];
    for (int l = 0; l < 4; ++l) {
        W[l]    = (const float*)d_in[2 + l * 4];
        Asrc[l] = (const float*)d_in[3 + l * 4];
        Adst[l] = (const float*)d_in[4 + l * 4];
        Bs[l]   = (const float*)d_in[5 + l * 4];
    }
    W[4] = W[3]; Asrc[4] = Asrc[3]; Adst[4] = Adst[3]; Bs[4] = Bs[3];

    char* ws = (char*)d_ws;
    size_t off = 0;
    auto alloc = [&](size_t bytes) -> void* {
        void* p = ws + off;
        off += (bytes + 255) & ~(size_t)255;
        return p;
    };
    _Float16* h16  = (_Float16*)alloc((size_t)N_NODES * HC * 2);
    float* xa      = (float*)alloc((size_t)N_NODES * HC * 4);
    float* xb      = (float*)alloc((size_t)N_NODES * HC * 4);
    float* xc      = (float*)alloc((size_t)N_NODES * HC * 4);
    float* es      = (float*)alloc((size_t)N_NODES * 4 * 4);
    float* ed      = (float*)alloc((size_t)N_NODES * 4 * 4);
    int*   counts  = (int*)alloc((size_t)N_NODES * 4);
    int*   offsets = (int*)alloc((size_t)(N_NODES + 1) * 4);
    int*   cursor  = (int*)alloc((size_t)N_NODES * 4);
    int*   csr_src = (int*)alloc((size_t)ETOT * 4);
    int*   blocksums = (int*)alloc((size_t)NBLK * 4);
    _Float16 *Wth[5], *Wtl[5];
    int Ks[4] = {128, 256, 256, 256};
    for (int l = 0; l < 4; ++l) {
        Wth[l] = (_Float16*)alloc((size_t)256 * Ks[l] * 2);
        Wtl[l] = (_Float16*)alloc((size_t)256 * Ks[l] * 2);
    }
    Wth[4] = Wth[3]; Wtl[4] = Wtl[3];

    hipMemsetAsync(counts, 0, (size_t)N_NODES * 4, stream);
    count_kernel<<<(ETOT + 255) / 256, 256, 0, stream>>>(ei, counts);
    blocksum_kernel<<<NBLK, 256, 0, stream>>>(counts, blocksums);
    blockscan_kernel<<<1, 64, 0, stream>>>(blocksums);
    scatter_scan_kernel<<<NBLK, 1024, 0, stream>>>(counts, blocksums, offsets, cursor);
    fill_kernel<<<(ETOT + 255) / 256, 256, 0, stream>>>(ei, cursor, csr_src);
    for (int l = 0; l < 4; ++l)
        wsplit_kernel<<<(Ks[l] * 256 + 255) / 256, 256, 0, stream>>>(W[l], Wth[l], Wtl[l], Ks[l]);

    auto layer = [&](const float* in1, const float* in2, int K, int l, float* outp, int relu) {
        gemm_mfma_kernel<<<(N_NODES + 63) / 64, 256, 0, stream>>>(
            in1, in2, Wth[l], Wtl[l], Asrc[l], Adst[l], h16, es, ed, N_NODES, K);
        gat_aggregate_kernel<<<N_NODES / 4, 256, 0, stream>>>(h16, es, ed, offsets, csr_src,
                                                              Bs[l], outp, relu);
    };

    float* out = (float*)d_out;
    layer(x,  nullptr, 128, 0, xa, 1);  // x1 = relu(gat(x))
    layer(xa, nullptr, 256, 1, xb, 1);  // x2 = relu(gat(x1))
    layer(xb, xa,      256, 2, xc, 1);  // x3 = relu(gat(x2+x1))
    layer(xb, xc,      256, 3, xa, 1);  // x4 = relu(gat(x2+x3))
    layer(xa, xc,      256, 4, out, 0); // x5 = gat(x4+x3), no relu
}

// Round 8
// 798.226 us; speedup vs baseline: 1.6608x; 1.0163x over previous
//
#include <hip/hip_runtime.h>
#include <hip/hip_bf16.h>

#define N_NODES 50000
#define E_EDGES 800000
#define ETOT (E_EDGES + N_NODES)
#define HC 256
#define NHEAD 4
#define CHAN 64
#define NEG 0.2f
#define NBLK ((N_NODES + 1023) / 1024)   // 49

typedef _Float16 half8 __attribute__((ext_vector_type(8)));
typedef _Float16 half4v __attribute__((ext_vector_type(4)));
typedef float float4v __attribute__((ext_vector_type(4)));

// ---------------- CSR build (once per call; shared across all 5 layers) ----------------

__global__ void count_kernel(const int* __restrict__ ei, int* __restrict__ counts) {
    int i = blockIdx.x * blockDim.x + threadIdx.x;
    if (i >= ETOT) return;
    int dst = (i < E_EDGES) ? ei[E_EDGES + i] : (i - E_EDGES);
    atomicAdd(&counts[dst], 1);
}

__global__ __launch_bounds__(256) void blocksum_kernel(const int* __restrict__ counts,
                                                       int* __restrict__ blocksums) {
    __shared__ int s[4];
    int b = blockIdx.x, tid = threadIdx.x;
    int base = b * 1024;
    int sum = 0;
    #pragma unroll
    for (int r = 0; r < 4; ++r) {
        int idx = base + r * 256 + tid;
        sum += (idx < N_NODES) ? counts[idx] : 0;
    }
    #pragma unroll
    for (int m = 1; m < 64; m <<= 1) sum += __shfl_xor(sum, m, 64);
    if ((tid & 63) == 0) s[tid >> 6] = sum;
    __syncthreads();
    if (tid == 0) blocksums[b] = s[0] + s[1] + s[2] + s[3];
}

__global__ __launch_bounds__(64) void blockscan_kernel(int* __restrict__ blocksums) {
    int tid = threadIdx.x;
    int v = (tid < NBLK) ? blocksums[tid] : 0;
    #pragma unroll
    for (int off = 1; off < 64; off <<= 1) {
        int t = __shfl_up(v, off, 64);
        if (tid >= off) v += t;
    }
    if (tid < NBLK) blocksums[tid] = v;   // inclusive
}

__global__ __launch_bounds__(1024) void scatter_scan_kernel(const int* __restrict__ counts,
                                                            const int* __restrict__ blocksums,
                                                            int* __restrict__ offsets,
                                                            int* __restrict__ cursor) {
    __shared__ int s[1024];
    int b = blockIdx.x, tid = threadIdx.x;
    int idx = b * 1024 + tid;
    int v = (idx < N_NODES) ? counts[idx] : 0;
    s[tid] = v;
    __syncthreads();
    for (int off = 1; off < 1024; off <<= 1) {
        int t = (tid >= off) ? s[tid - off] : 0;
        __syncthreads();
        s[tid] += t;
        __syncthreads();
    }
    int excl = s[tid] - v + (b > 0 ? blocksums[b - 1] : 0);
    if (idx < N_NODES) { offsets[idx] = excl; cursor[idx] = excl; }
    if (idx == N_NODES - 1) offsets[N_NODES] = excl + v;
}

__global__ void fill_kernel(const int* __restrict__ ei, int* __restrict__ cursor,
                            int* __restrict__ csr_src) {
    int i = blockIdx.x * blockDim.x + threadIdx.x;
    if (i >= ETOT) return;
    int src, dst;
    if (i < E_EDGES) { src = ei[i]; dst = ei[E_EDGES + i]; }
    else             { src = i - E_EDGES; dst = src; }
    int pos = atomicAdd(&cursor[dst], 1);
    csr_src[pos] = src;
}

// ---------------- pre-splits: W[K][256] -> Wt hi/lo [n][k]; x -> xh/xl f16 ----------------

__global__ void wsplit_kernel(const float* __restrict__ W, _Float16* __restrict__ Wth,
                              _Float16* __restrict__ Wtl, int K) {
    int id = blockIdx.x * 256 + threadIdx.x;
    if (id >= K * 256) return;
    int n = id & 255, k = id >> 8;
    float w = W[(size_t)k * 256 + n];
    _Float16 h = (_Float16)w;
    _Float16 l = (_Float16)(w - (float)h);
    Wth[(size_t)n * K + k] = h;
    Wtl[(size_t)n * K + k] = l;
}

__global__ void xsplit_kernel(const float* __restrict__ x, _Float16* __restrict__ xh,
                              _Float16* __restrict__ xl, int total) {
    int id = blockIdx.x * 256 + threadIdx.x;
    if (id >= total) return;
    float v = x[id];
    _Float16 h = (_Float16)v;
    xh[id] = h;
    xl[id] = (_Float16)(v - (float)h);
}

// ---------------- f16 MFMA GEMM + fused es/ed epilogue ----------------
// BM=64, BN=256 (A read once), BK=32, 256 thr / 4 waves; wave w = head w.
// A inputs are f16 (A1h [+A1l lo-part, layer 1] [+A2h residual]).
// W kept as hi/lo f16 pair => weight fidelity ~fp32. 2-MFMA chain (3 w/ A-lo).

#define LDK 40

__global__ __launch_bounds__(256) void gemm_mfma_kernel(
        const _Float16* __restrict__ A1h, const _Float16* __restrict__ A1l,
        const _Float16* __restrict__ A2h,
        const _Float16* __restrict__ Wth, const _Float16* __restrict__ Wtl,
        const float* __restrict__ a_src, const float* __restrict__ a_dst,
        _Float16* __restrict__ H16, float* __restrict__ es, float* __restrict__ ed,
        int M, int K) {
    __shared__ _Float16 Ah[64][LDK];
    __shared__ _Float16 Al[64][LDK];
    __shared__ _Float16 Bh[256][LDK];
    __shared__ _Float16 Bl[256][LDK];

    int tid = threadIdx.x;
    int m0 = blockIdx.x * 64;
    int w = tid >> 6, lane = tid & 63;
    int rn = w * 64;
    int fr = lane & 15;
    int q  = lane >> 4;
    int fk = q * 8;

    int wr = tid >> 2;            // 0..63 (A/B: 4 thr/row)
    int wk = (tid & 3) * 8;       // 0,8,16,24

    bool has_lo = (A1l != nullptr);
    bool has2   = (A2h != nullptr);

    float4v acc[4][4];
    #pragma unroll
    for (int i = 0; i < 4; ++i)
        #pragma unroll
        for (int j = 0; j < 4; ++j)
            acc[i][j] = (float4v){0.f, 0.f, 0.f, 0.f};

    half8 pa, pal, pbh[4], pbl[4];

    auto load_tile = [&](int k0) {
        int row = m0 + wr;
        pa  = (half8)(_Float16)0;
        pal = (half8)(_Float16)0;
        if (row < M) {
            pa = *(const half8*)(A1h + (size_t)row * K + k0 + wk);
            if (has2) {
                half8 u = *(const half8*)(A2h + (size_t)row * K + k0 + wk);
                pa = pa + u;
            }
            if (has_lo) pal = *(const half8*)(A1l + (size_t)row * K + k0 + wk);
        }
        #pragma unroll
        for (int g = 0; g < 4; ++g) {
            int r = g * 64 + wr;
            pbh[g] = *(const half8*)(Wth + (size_t)r * K + k0 + wk);
            pbl[g] = *(const half8*)(Wtl + (size_t)r * K + k0 + wk);
        }
    };

    load_tile(0);
    for (int k0 = 0; k0 < K; k0 += 32) {
        *(half8*)&Ah[wr][wk] = pa;
        if (has_lo) *(half8*)&Al[wr][wk] = pal;
        #pragma unroll
        for (int g = 0; g < 4; ++g) {
            int r = g * 64 + wr;
            *(half8*)&Bh[r][wk] = pbh[g];
            *(half8*)&Bl[r][wk] = pbl[g];
        }
        __syncthreads();
        // prefetch next tile: loads in flight across the MFMA phase
        if (k0 + 32 < K) load_tile(k0 + 32);
        half8 afh[4], bfh[4], bfl[4];
        #pragma unroll
        for (int t = 0; t < 4; ++t) {
            afh[t] = *(const half8*)&Ah[t * 16 + fr][fk];
            bfh[t] = *(const half8*)&Bh[rn + t * 16 + fr][fk];
            bfl[t] = *(const half8*)&Bl[rn + t * 16 + fr][fk];
        }
        if (has_lo) {
            half8 afl[4];
            #pragma unroll
            for (int t = 0; t < 4; ++t) afl[t] = *(const half8*)&Al[t * 16 + fr][fk];
            #pragma unroll
            for (int tm = 0; tm < 4; ++tm)
                #pragma unroll
                for (int tn = 0; tn < 4; ++tn)
                    acc[tm][tn] = __builtin_amdgcn_mfma_f32_16x16x32_f16(
                        afl[tm], bfh[tn], acc[tm][tn], 0, 0, 0);
        }
        #pragma unroll
        for (int tm = 0; tm < 4; ++tm)
            #pragma unroll
            for (int tn = 0; tn < 4; ++tn) {
                float4v c = acc[tm][tn];
                c = __builtin_amdgcn_mfma_f32_16x16x32_f16(afh[tm], bfl[tn], c, 0, 0, 0);
                c = __builtin_amdgcn_mfma_f32_16x16x32_f16(afh[tm], bfh[tn], c, 0, 0, 0);
                acc[tm][tn] = c;
            }
        __syncthreads();
    }

    // ---- epilogue: H16 write + fused es/ed (wave w == head w) ----
    float asv[4], adv[4];
    #pragma unroll
    for (int tn = 0; tn < 4; ++tn) {
        asv[tn] = a_src[w * CHAN + tn * 16 + fr];
        adv[tn] = a_dst[w * CHAN + tn * 16 + fr];
    }
    #pragma unroll
    for (int tm = 0; tm < 4; ++tm) {
        #pragma unroll
        for (int i = 0; i < 4; ++i) {
            int row = m0 + tm * 16 + q * 4 + i;
            float ps = 0.f, pd = 0.f;
            #pragma unroll
            for (int tn = 0; tn < 4; ++tn) {
                float hv = acc[tm][tn][i];
                ps += hv * asv[tn];
                pd += hv * adv[tn];
                if (row < M)
                    H16[(size_t)row * HC + rn + tn * 16 + fr] = (_Float16)hv;
            }
            #pragma unroll
            for (int msk = 1; msk < 16; msk <<= 1) {
                ps += __shfl_xor(ps, msk, 64);
                pd += __shfl_xor(pd, msk, 64);
            }
            if (fr == 0 && row < M) {
                es[row * NHEAD + w] = ps;
                ed[row * NHEAD + w] = pd;
            }
        }
    }
}

// ---------------- fused edge-softmax + aggregation: ONE WAVE per dst node ----------------
// out16 != null => write f16 intermediate; else fp32 final.

__global__ __launch_bounds__(256) void gat_aggregate_kernel(
        const _Float16* __restrict__ H16, const float* __restrict__ es, const float* __restrict__ ed,
        const int* __restrict__ offsets, const int* __restrict__ csr_src,
        const float* __restrict__ bias, _Float16* __restrict__ out16,
        float* __restrict__ out32, int do_relu) {
    __shared__ float alpha_lds[4][256];
    int tid = threadIdx.x;
    int w = tid >> 6, lane = tid & 63;
    int n = blockIdx.x * 4 + w;
    int off = offsets[n];
    int deg = offsets[n + 1] - off;
    float4 edv = *(const float4*)(ed + (size_t)n * 4);

    if (deg <= 64) {
        // --- softmax: lane = edge ---
        int sreg = 0;
        float4 e4 = make_float4(-1e30f, -1e30f, -1e30f, -1e30f);
        if (lane < deg) {
            sreg = csr_src[off + lane];
            float4 esv = *(const float4*)(es + (size_t)sreg * 4);
            e4.x = esv.x + edv.x; e4.y = esv.y + edv.y;
            e4.z = esv.z + edv.z; e4.w = esv.w + edv.w;
            e4.x = (e4.x > 0.f) ? e4.x : NEG * e4.x;
            e4.y = (e4.y > 0.f) ? e4.y : NEG * e4.y;
            e4.z = (e4.z > 0.f) ? e4.z : NEG * e4.z;
            e4.w = (e4.w > 0.f) ? e4.w : NEG * e4.w;
        }
        float4 m4 = e4;
        #pragma unroll
        for (int msk = 1; msk < 64; msk <<= 1) {
            m4.x = fmaxf(m4.x, __shfl_xor(m4.x, msk, 64));
            m4.y = fmaxf(m4.y, __shfl_xor(m4.y, msk, 64));
            m4.z = fmaxf(m4.z, __shfl_xor(m4.z, msk, 64));
            m4.w = fmaxf(m4.w, __shfl_xor(m4.w, msk, 64));
        }
        float4 ex4 = make_float4(0.f, 0.f, 0.f, 0.f);
        if (lane < deg) {
            ex4.x = __expf(e4.x - m4.x); ex4.y = __expf(e4.y - m4.y);
            ex4.z = __expf(e4.z - m4.z); ex4.w = __expf(e4.w - m4.w);
        }
        float4 l4 = ex4;
        #pragma unroll
        for (int msk = 1; msk < 64; msk <<= 1) {
            l4.x += __shfl_xor(l4.x, msk, 64);
            l4.y += __shfl_xor(l4.y, msk, 64);
            l4.z += __shfl_xor(l4.z, msk, 64);
            l4.w += __shfl_xor(l4.w, msk, 64);
        }
        float4 a4;
        a4.x = ex4.x / (l4.x + 1e-16f);
        a4.y = ex4.y / (l4.y + 1e-16f);
        a4.z = ex4.z / (l4.z + 1e-16f);
        a4.w = ex4.w / (l4.w + 1e-16f);
        *(float4*)&alpha_lds[w][lane * 4] = a4;   // same-wave write+read: no barrier

        // --- gather: 2 edges per wave; 32 lanes x 8 channels (16B loads) ---
        int hl = lane & 31, side = lane >> 5;
        int hd = hl >> 3;
        float av[8] = {0.f, 0.f, 0.f, 0.f, 0.f, 0.f, 0.f, 0.f};
        #pragma unroll 2
        for (int j = side; j < deg; j += 2) {
            int s = __shfl(sreg, j, 64);
            float al = alpha_lds[w][j * 4 + hd];
            half8 hv = *(const half8*)(H16 + (size_t)s * HC + hl * 8);
            #pragma unroll
            for (int c = 0; c < 8; ++c) av[c] += al * (float)hv[c];
        }
        #pragma unroll
        for (int c = 0; c < 8; ++c) av[c] += __shfl_xor(av[c], 32, 64);
        if (side == 0) {
            float4 b0 = *(const float4*)(bias + hl * 8);
            float4 b1 = *(const float4*)(bias + hl * 8 + 4);
            float o[8] = {av[0] + b0.x, av[1] + b0.y, av[2] + b0.z, av[3] + b0.w,
                          av[4] + b1.x, av[5] + b1.y, av[6] + b1.z, av[7] + b1.w};
            if (do_relu)
                #pragma unroll
                for (int c = 0; c < 8; ++c) o[c] = fmaxf(o[c], 0.f);
            if (out16) {
                half8 ov = {(_Float16)o[0], (_Float16)o[1], (_Float16)o[2], (_Float16)o[3],
                            (_Float16)o[4], (_Float16)o[5], (_Float16)o[6], (_Float16)o[7]};
                *(half8*)(out16 + (size_t)n * HC + hl * 8) = ov;
            } else {
                *(float4*)(out32 + (size_t)n * HC + hl * 8) =
                    make_float4(o[0], o[1], o[2], o[3]);
                *(float4*)(out32 + (size_t)n * HC + hl * 8 + 4) =
                    make_float4(o[4], o[5], o[6], o[7]);
            }
        }
        return;
    }

    // --- generic fallback (deg > 64): 4 channels/lane ---
    int head = lane >> 4;
    float4 acc0 = make_float4(0.f, 0.f, 0.f, 0.f);
    float m[4] = {-1e30f, -1e30f, -1e30f, -1e30f};
    float l[4] = {0.f, 0.f, 0.f, 0.f};
    for (int base = 0; base < deg; base += 64) {
        int j = base + lane;
        if (j < deg) {
            int s = csr_src[off + j];
            float4 esv = *(const float4*)(es + (size_t)s * 4);
            float e[4] = {esv.x + edv.x, esv.y + edv.y, esv.z + edv.z, esv.w + edv.w};
            #pragma unroll
            for (int h = 0; h < 4; ++h) {
                e[h] = (e[h] > 0.f) ? e[h] : NEG * e[h];
                float M2 = fmaxf(m[h], e[h]);
                l[h] = l[h] * __expf(m[h] - M2) + __expf(e[h] - M2);
                m[h] = M2;
            }
        }
    }
    #pragma unroll
    for (int msk = 1; msk < 64; msk <<= 1) {
        #pragma unroll
        for (int h = 0; h < 4; ++h) {
            float mo = __shfl_xor(m[h], msk, 64);
            float lo = __shfl_xor(l[h], msk, 64);
            float M2 = fmaxf(m[h], mo);
            l[h] = l[h] * __expf(m[h] - M2) + lo * __expf(mo - M2);
            m[h] = M2;
        }
    }
    float fm = m[head];
    float fr2 = 1.f / (l[head] + 1e-16f);
    float edh = ((const float*)&edv)[head];
    for (int j = 0; j < deg; ++j) {
        int s = csr_src[off + j];
        float e = es[(size_t)s * 4 + head] + edh;
        e = (e > 0.f) ? e : NEG * e;
        float alpha = __expf(e - fm) * fr2;
        half4v h0 = *(const half4v*)(H16 + (size_t)s * HC + lane * 4);
        acc0.x += alpha * (float)h0[0]; acc0.y += alpha * (float)h0[1];
        acc0.z += alpha * (float)h0[2]; acc0.w += alpha * (float)h0[3];
    }
    float4 b4 = *(const float4*)(bias + lane * 4);
    float o[4] = {acc0.x + b4.x, acc0.y + b4.y, acc0.z + b4.z, acc0.w + b4.w};
    if (do_relu)
        #pragma unroll
        for (int c = 0; c < 4; ++c) o[c] = fmaxf(o[c], 0.f);
    if (out16) {
        half4v ov = {(_Float16)o[0], (_Float16)o[1], (_Float16)o[2], (_Float16)o[3]};
        *(half4v*)(out16 + (size_t)n * HC + lane * 4) = ov;
    } else {
        *(float4*)(out32 + (size_t)n * HC + lane * 4) = make_float4(o[0], o[1], o[2], o[3]);
    }
}

// ---------------- launch ----------------

extern "C" void kernel_launch(void* const* d_in, const int* in_sizes, int n_in,
                              void* d_out, int out_size, void* d_ws, size_t ws_size,
                              hipStream_t stream) {
    const float* x  = (const float*)d_in[0];
    const int*   ei = (const int*)d_in[1];
    const float *W[5], *Asrc[5], *Adst[5], *Bs[5];
    for (int l = 0; l < 4; ++l) {
        W[l]    = (const float*)d_in[2 + l * 4];
        Asrc[l] = (const float*)d_in[3 + l * 4];
        Adst[l] = (const float*)d_in[4 + l * 4];
        Bs[l]   = (const float*)d_in[5 + l * 4];
    }
    W[4] = W[3]; Asrc[4] = Asrc[3]; Adst[4] = Adst[3]; Bs[4] = Bs[3];

    char* ws = (char*)d_ws;
    size_t off = 0;
    auto alloc = [&](size_t bytes) -> void* {
        void* p = ws + off;
        off += (bytes + 255) & ~(size_t)255;
        return p;
    };
    _Float16* h16  = (_Float16*)alloc((size_t)N_NODES * HC * 2);
    _Float16* xa   = (_Float16*)alloc((size_t)N_NODES * HC * 2);
    _Float16* xb   = (_Float16*)alloc((size_t)N_NODES * HC * 2);
    _Float16* xc   = (_Float16*)alloc((size_t)N_NODES * HC * 2);
    _Float16* xd   = (_Float16*)alloc((size_t)N_NODES * HC * 2);
    _Float16* xh   = (_Float16*)alloc((size_t)N_NODES * 128 * 2);
    _Float16* xl   = (_Float16*)alloc((size_t)N_NODES * 128 * 2);
    float* es      = (float*)alloc((size_t)N_NODES * 4 * 4);
    float* ed      = (float*)alloc((size_t)N_NODES * 4 * 4);
    int*   counts  = (int*)alloc((size_t)N_NODES * 4);
    int*   offsets = (int*)alloc((size_t)(N_NODES + 1) * 4);
    int*   cursor  = (int*)alloc((size_t)N_NODES * 4);
    int*   csr_src = (int*)alloc((size_t)ETOT * 4);
    int*   blocksums = (int*)alloc((size_t)NBLK * 4);
    _Float16 *Wth[5], *Wtl[5];
    int Ks[4] = {128, 256, 256, 256};
    for (int l = 0; l < 4; ++l) {
        Wth[l] = (_Float16*)alloc((size_t)256 * Ks[l] * 2);
        Wtl[l] = (_Float16*)alloc((size_t)256 * Ks[l] * 2);
    }
    Wth[4] = Wth[3]; Wtl[4] = Wtl[3];

    hipMemsetAsync(counts, 0, (size_t)N_NODES * 4, stream);
    count_kernel<<<(ETOT + 255) / 256, 256, 0, stream>>>(ei, counts);
    blocksum_kernel<<<NBLK, 256, 0, stream>>>(counts, blocksums);
    blockscan_kernel<<<1, 64, 0, stream>>>(blocksums);
    scatter_scan_kernel<<<NBLK, 1024, 0, stream>>>(counts, blocksums, offsets, cursor);
    fill_kernel<<<(ETOT + 255) / 256, 256, 0, stream>>>(ei, cursor, csr_src);
    for (int l = 0; l < 4; ++l)
        wsplit_kernel<<<(Ks[l] * 256 + 255) / 256, 256, 0, stream>>>(W[l], Wth[l], Wtl[l], Ks[l]);
    xsplit_kernel<<<(N_NODES * 128 + 255) / 256, 256, 0, stream>>>(x, xh, xl, N_NODES * 128);

    auto layer = [&](const _Float16* a1h, const _Float16* a1l, const _Float16* a2h,
                     int K, int l, _Float16* o16, float* o32, int relu) {
        gemm_mfma_kernel<<<(N_NODES + 63) / 64, 256, 0, stream>>>(
            a1h, a1l, a2h, Wth[l], Wtl[l], Asrc[l], Adst[l], h16, es, ed, N_NODES, K);
        gat_aggregate_kernel<<<N_NODES / 4, 256, 0, stream>>>(
            h16, es, ed, offsets, csr_src, Bs[l], o16, o32, relu);
    };

    float* out = (float*)d_out;
    layer(xh, xl,      nullptr, 128, 0, xa, nullptr, 1);  // x1 = relu(gat(x))
    layer(xa, nullptr, nullptr, 256, 1, xb, nullptr, 1);  // x2 = relu(gat(x1))
    layer(xb, nullptr, xa,      256, 2, xc, nullptr, 1);  // x3 = relu(gat(x2+x1))
    layer(xb, nullptr, xc,      256, 3, xd, nullptr, 1);  // x4 = relu(gat(x2+x3))
    layer(xd, nullptr, xc,      256, 4, nullptr, out, 0); // x5 = gat(x4+x3), no relu
}